// Round 7
// baseline (1859.048 us; speedup 1.0000x reference)
//
#include <hip/hip_runtime.h>
#include <hip/hip_bf16.h>

#define L 1152
#define NRES 384
#define CS 256
#define CZ 128
#define H 8
#define CH 16
#define PQ 8
#define PV 12
#define PSTR 1088   // padded projection row stride (17*64)

// workspace offsets (in floats)
#define OFF_SLN  0L          // 1152*256      = 294912
#define OFF_PROJ 294912L     // 1152*1088     = 1253376
#define OFF_WPK  1548288L    // 256*1088      = 278528
#define OFF_QCAT 1826816L    // 8*1152*44     = 405504
#define OFF_KCAT 2232320L    // 8*1152*44     = 405504
#define OFF_VCAT 2637824L    // 8*1152*64     = 589824
#define OFF_BRES 3227648L    // 8*147456      = 1179648 (transposed [h][rp])
#define OFF_MURS 4407296L    // 384*384*2     = 294912
#define OFF_ATTN 4702208L    // 8*1152*1152   = 10616832
#define OFF_CAT  15319040L   // 1152*1536     = 1769472
// total fp32: 17088512 floats = 68.4 MB

// ---------------- kernel 1: LayerNorm(s) -> fp32 -------------------
__global__ __launch_bounds__(256) void k_ln_s(const float* s, const float* sc, const float* bi, float* sln){
  int l = blockIdx.x, t = threadIdx.x;
  __shared__ float red[CS];
  float x = s[(long)l*CS + t];
  red[t] = x; __syncthreads();
  for(int st=128; st>0; st>>=1){ if(t<st) red[t]+=red[t+st]; __syncthreads(); }
  float mu = red[0] * (1.f/CS); __syncthreads();
  float d = x - mu;
  red[t] = d*d; __syncthreads();
  for(int st=128; st>0; st>>=1){ if(t<st) red[t]+=red[t+st]; __syncthreads(); }
  float var = red[0]*(1.f/CS);
  sln[(long)l*CS + t] = d*rsqrtf(var + 1e-5f)*sc[t] + bi[t];
}

// ---------------- kernel 1b: pack six weight mats into wpack[256][1088]
__global__ __launch_bounds__(256) void k_packw(const float* wq, const float* wk, const float* wv,
                        const float* wqp, const float* wkp, const float* wvp, float* wpack){
  int k = blockIdx.x, t = threadIdx.x;
  for(int c=t; c<PSTR; c+=256){
    float v;
    if(c<128)        v = wq [(long)k*128 + c];
    else if(c<256)   v = wk [(long)k*128 + c-128];
    else if(c<384)   v = wv [(long)k*128 + c-256];
    else if(c<576)   v = wqp[(long)k*192 + c-384];
    else if(c<768)   v = wkp[(long)k*192 + c-576];
    else if(c<1056)  v = wvp[(long)k*288 + c-768];
    else             v = 0.f;
    wpack[(long)k*PSTR + c] = v;
  }
}

// ---------------- kernel 2: projections as tiled GEMM --------------
__global__ __launch_bounds__(256) void k_proj(const float* sln, const float* wpack, float* proj){
  int l0 = blockIdx.x*64, c0 = blockIdx.y*64, t = threadIdx.x;
  __shared__ float a_s[32][68];
  __shared__ __align__(16) float w_s[32][68];
  int tr = t>>4, tc = t&15;
  float4 acc[4] = {{0,0,0,0},{0,0,0,0},{0,0,0,0},{0,0,0,0}};
  for(int kc=0; kc<8; kc++){
    int k0 = kc*32;
    {
      int row = t>>2, kk0 = (t&3)*8;
      const float4* src = (const float4*)(sln + (long)(l0+row)*256 + k0 + kk0);
      float4 v0 = src[0], v1 = src[1];
      a_s[kk0+0][row]=v0.x; a_s[kk0+1][row]=v0.y; a_s[kk0+2][row]=v0.z; a_s[kk0+3][row]=v0.w;
      a_s[kk0+4][row]=v1.x; a_s[kk0+5][row]=v1.y; a_s[kk0+6][row]=v1.z; a_s[kk0+7][row]=v1.w;
    }
    #pragma unroll
    for(int kk2=0; kk2<2; kk2++){
      int kk = (t>>4) + 16*kk2;
      *(float4*)&w_s[kk][(t&15)*4] = *(const float4*)(wpack + (long)(k0+kk)*PSTR + c0 + (t&15)*4);
    }
    __syncthreads();
    #pragma unroll 8
    for(int kk=0; kk<32; kk++){
      float4 a4 = *(const float4*)&a_s[kk][tr*4];
      float4 b4 = *(const float4*)&w_s[kk][tc*4];
      acc[0].x+=a4.x*b4.x; acc[0].y+=a4.x*b4.y; acc[0].z+=a4.x*b4.z; acc[0].w+=a4.x*b4.w;
      acc[1].x+=a4.y*b4.x; acc[1].y+=a4.y*b4.y; acc[1].z+=a4.y*b4.z; acc[1].w+=a4.y*b4.w;
      acc[2].x+=a4.z*b4.x; acc[2].y+=a4.z*b4.y; acc[2].z+=a4.z*b4.z; acc[2].w+=a4.z*b4.w;
      acc[3].x+=a4.w*b4.x; acc[3].y+=a4.w*b4.y; acc[3].z+=a4.w*b4.z; acc[3].w+=a4.w*b4.w;
    }
    __syncthreads();
  }
  #pragma unroll
  for(int r=0;r<4;r++)
    *(float4*)(proj + (long)(l0 + tr*4 + r)*PSTR + c0 + tc*4) = acc[r];
}

// ---------------- kernel 3: LayerNorm(z) stats + b_res = z_ln @ w_b
__global__ __launch_bounds__(256) void k_ln_z(const float* z, const float* sc, const float* bi,
                       const float* wb, float* murs, float* bres_t){
  int t = threadIdx.x;
  long rp0 = (long)blockIdx.x*32;
  int r = t>>3, part = t&7;
  long rp = rp0 + r;
  __shared__ __align__(16) float swb[8*132];   // [h][c] padded to 132
  __shared__ float SB[8][2];
  const float4* z4 = (const float4*)z;
  float4 x0 = z4[rp*32 + part*4 + 0];
  float4 x1 = z4[rp*32 + part*4 + 1];
  float4 x2 = z4[rp*32 + part*4 + 2];
  float4 x3 = z4[rp*32 + part*4 + 3];
  #pragma unroll
  for(int k2=0;k2<4;k2++){
    int e = t + k2*256; int h = e>>7, c = e&127;
    swb[h*132 + c] = sc[c]*wb[(long)c*8 + h];
  }
  __syncthreads();
  if(t < 64){
    int h = t>>3, seg = t&7;
    float S=0, Bv=0;
    #pragma unroll
    for(int i=0;i<16;i++){
      int c = seg*16+i;
      S  += swb[h*132+c];
      Bv += bi[c]*wb[(long)c*8 + h];
    }
    #pragma unroll
    for(int off=1;off<8;off<<=1){ S += __shfl_xor(S,off,64); Bv += __shfl_xor(Bv,off,64); }
    if(seg==0){ SB[h][0]=S; SB[h][1]=Bv; }
  }
  float s1 = x0.x+x0.y+x0.z+x0.w + x1.x+x1.y+x1.z+x1.w
           + x2.x+x2.y+x2.z+x2.w + x3.x+x3.y+x3.z+x3.w;
  float s2 = x0.x*x0.x+x0.y*x0.y+x0.z*x0.z+x0.w*x0.w
           + x1.x*x1.x+x1.y*x1.y+x1.z*x1.z+x1.w*x1.w
           + x2.x*x2.x+x2.y*x2.y+x2.z*x2.z+x2.w*x2.w
           + x3.x*x3.x+x3.y*x3.y+x3.z*x3.z+x3.w*x3.w;
  #pragma unroll
  for(int off=1;off<8;off<<=1){ s1 += __shfl_xor(s1,off,64); s2 += __shfl_xor(s2,off,64); }
  float mu = s1*(1.f/CZ);
  float var = s2*(1.f/CZ) - mu*mu;
  float rstd = rsqrtf(var + 1e-5f);
  if(part==0){ murs[rp*2]=mu; murs[rp*2+1]=rstd; }
  float acc[8];
  const float4* swb4 = (const float4*)swb;  // 33 float4 per h-row
  #pragma unroll
  for(int h=0;h<8;h++){
    float4 wa = swb4[h*33 + part*4 + 0];
    float4 wbv= swb4[h*33 + part*4 + 1];
    float4 wc = swb4[h*33 + part*4 + 2];
    float4 wd = swb4[h*33 + part*4 + 3];
    acc[h] = x0.x*wa.x + x0.y*wa.y + x0.z*wa.z + x0.w*wa.w
           + x1.x*wbv.x+ x1.y*wbv.y+ x1.z*wbv.z+ x1.w*wbv.w
           + x2.x*wc.x + x2.y*wc.y + x2.z*wc.z + x2.w*wc.w
           + x3.x*wd.x + x3.y*wd.y + x3.z*wd.z + x3.w*wd.w;
  }
  #pragma unroll
  for(int off=1;off<8;off<<=1){
    #pragma unroll
    for(int h=0;h<8;h++) acc[h] += __shfl_xor(acc[h],off,64);
  }
  __syncthreads();
  if(part==0){
    #pragma unroll
    for(int h=0;h<8;h++)
      bres_t[(long)h*147456 + rp] = rstd*(acc[h] - mu*SB[h][0]) + SB[h][1];
  }
}

// ---------------- kernel 4: rigid transforms + score-vector packing
__global__ __launch_bounds__(256) void k_rigid(const float* proj, const float* rot, const float* trans,
                        const float* mask, const float* hws,
                        float* qcat, float* kcat, float* vcat){
  int l = blockIdx.x, t = threadIdx.x;
  __shared__ float R[9], T[3], hwS[8], qgs[192], kgs[192];
  if(t<9) R[t]=rot[(long)l*9+t];
  if(t<3) T[t]=trans[(long)l*3+t];
  if(t>=16 && t<24) hwS[t-16] = log1pf(expf(hws[t-16]))*0.09622504486493764f;
  __syncthreads();
  const float* pr = proj + (long)l*PSTR;
  if(t<128){
    int h=t>>4, c=t&15;
    long base = ((long)h*L + l)*44;
    qcat[base + c] = 0.14433756729740643f * pr[t];
    kcat[base + c] = pr[128+t];
    vcat[((long)h*L + l)*64 + c] = pr[256+t];
  }
  if(t < 192){
    int h=t/24, m=t%24, p=m/3, i=m%3;
    float qa = R[i*3+0]*pr[384+h*24+p*3+0] + R[i*3+1]*pr[384+h*24+p*3+1]
             + R[i*3+2]*pr[384+h*24+p*3+2] + T[i];
    float ka = R[i*3+0]*pr[576+h*24+p*3+0] + R[i*3+1]*pr[576+h*24+p*3+1]
             + R[i*3+2]*pr[576+h*24+p*3+2] + T[i];
    qgs[t]=qa; kgs[t]=ka;
    long base = ((long)h*L + l)*44 + 16 + m;
    qcat[base] = hwS[h]*qa;
    kcat[base] = ka;
  }
  for(int it=t; it<288; it+=256){
    int h=it/36, m=it%36, p=m/3, i=m%3;
    float a = R[i*3+0]*pr[768+h*36+p*3+0] + R[i*3+1]*pr[768+h*36+p*3+1]
            + R[i*3+2]*pr[768+h*36+p*3+2] + T[i];
    vcat[((long)h*L + l)*64 + 16 + m] = a;
  }
  if(t < 96){
    int h=t/12, d=t%12;
    vcat[((long)h*L + l)*64 + 52 + d] = 0.f;
  }
  __syncthreads();
  if(t < 8){
    float qq=0, kk=0;
    #pragma unroll
    for(int m=0;m<24;m++){ qq += qgs[t*24+m]*qgs[t*24+m]; kk += kgs[t*24+m]*kgs[t*24+m]; }
    long base = ((long)t*L + l)*44;
    qcat[base + 40] = -0.5f*hwS[t]*qq;
    kcat[base + 40] = -0.5f*hwS[t]*kk + (mask[l]-1.f)*1e9f;
  }
}

// ---------------- kernel 5: scores GEMM (K=40) + fused softmax -----
// block: 16 l-rows x full j for one h. Thread (lgrp,jgrp) 16x16.
// Fully unrolled jc loop + float4 score array => all-static register
// indexing, no scratch spill. launch_bounds(256,2) caps VGPR at 256.
__global__ __launch_bounds__(256, 2) void k_scores(const float* qcat, const float* kcat,
                         const float* bres_t, const int* ridx, float* attn){
  int lb = blockIdx.x, h = blockIdx.y, t = threadIdx.x;
  int lgrp = t>>4, jgrp = t&15;
  int l = lb*16 + lgrp;
  __shared__ __align__(16) float ks[64*44];
  __shared__ int rj_s[64];
  float4 q[10];
  const float4* qrow = (const float4*)(qcat + ((long)h*L + l)*44);
  #pragma unroll
  for(int i=0;i<10;i++) q[i]=qrow[i];
  float rowc = qcat[((long)h*L + l)*44 + 40];
  int rl = ridx[l];
  const float* bb = bres_t + (long)h*147456 + (long)rl*NRES;
  float4 sc4[18];
  #pragma unroll
  for(int jc=0;jc<18;jc++){
    int j0=jc*64;
    __syncthreads();
    {
      const float* src = kcat + ((long)h*L + j0)*44;
      #pragma unroll
      for(int i=0;i<11;i++) ks[t + i*256] = src[t + i*256];
      if(t<64) rj_s[t]=ridx[j0+t];
    }
    __syncthreads();
    float dv[4];
    #pragma unroll
    for(int jj=0;jj<4;jj++){
      int jcol = jgrp + 16*jj;
      const float4* kv = (const float4*)&ks[jcol*44];
      float d=0;
      #pragma unroll
      for(int i=0;i<10;i++){
        float4 a=q[i], b=kv[i];
        d += a.x*b.x + a.y*b.y + a.z*b.z + a.w*b.w;
      }
      float colc = ks[jcol*44+40];
      float bias = bb[rj_s[jcol]];
      dv[jj] = d + rowc + colc + 0.5773502691896258f*bias;
    }
    sc4[jc].x=dv[0]; sc4[jc].y=dv[1]; sc4[jc].z=dv[2]; sc4[jc].w=dv[3];
  }
  float m = -1e30f;
  #pragma unroll
  for(int i=0;i<18;i++)
    m = fmaxf(m, fmaxf(fmaxf(sc4[i].x,sc4[i].y), fmaxf(sc4[i].z,sc4[i].w)));
  #pragma unroll
  for(int off=1;off<16;off<<=1) m = fmaxf(m, __shfl_xor(m, off, 64));
  float s=0;
  #pragma unroll
  for(int i=0;i<18;i++){
    sc4[i].x=__expf(sc4[i].x-m); sc4[i].y=__expf(sc4[i].y-m);
    sc4[i].z=__expf(sc4[i].z-m); sc4[i].w=__expf(sc4[i].w-m);
    s += sc4[i].x+sc4[i].y+sc4[i].z+sc4[i].w;
  }
  #pragma unroll
  for(int off=1;off<16;off<<=1) s += __shfl_xor(s, off, 64);
  float inv=1.f/s;
  float* arow = attn + ((long)h*L + l)*L;
  #pragma unroll
  for(int jc=0;jc<18;jc++){
    arow[jc*64 + jgrp +  0] = sc4[jc].x*inv;
    arow[jc*64 + jgrp + 16] = sc4[jc].y*inv;
    arow[jc*64 + jgrp + 32] = sc4[jc].z*inv;
    arow[jc*64 + jgrp + 48] = sc4[jc].w*inv;
  }
}

// ---------------- kernel 6: tiled GEMM o|o_pt + epilogue -----------
__global__ __launch_bounds__(256) void k_av(const float* attn, const float* vcat,
                     const float* rot, const float* trans, float* cat){
  int lb = blockIdx.x, h = blockIdx.y, t = threadIdx.x;
  int l0 = lb*32;
  __shared__ float a_s[64][33];
  __shared__ __align__(16) float v_s[64][68];
  __shared__ __align__(16) float fin_s[32][64];
  int lgrp = t>>4, dgrp = t&15;   // 16 x 16
  float4 acc0 = {0,0,0,0}, acc1 = {0,0,0,0};
  const float* abase = attn + ((long)h*L + l0)*L;
  for(int jc=0; jc<18; jc++){
    int j0 = jc*64;
    {
      int al = t>>3, jj0 = (t&7)*8;
      const float4* src = (const float4*)(abase + (long)al*L + j0 + jj0);
      float4 p0 = src[0], p1 = src[1];
      a_s[jj0+0][al]=p0.x; a_s[jj0+1][al]=p0.y; a_s[jj0+2][al]=p0.z; a_s[jj0+3][al]=p0.w;
      a_s[jj0+4][al]=p1.x; a_s[jj0+5][al]=p1.y; a_s[jj0+6][al]=p1.z; a_s[jj0+7][al]=p1.w;
    }
    {
      int jj = t>>2, seg = t&3;
      const float4* src = (const float4*)(vcat + ((long)h*L + j0 + jj)*64 + seg*16);
      float4 q0=src[0], q1=src[1], q2=src[2], q3=src[3];
      float4* dst = (float4*)&v_s[jj][seg*16];
      dst[0]=q0; dst[1]=q1; dst[2]=q2; dst[3]=q3;
    }
    __syncthreads();
    #pragma unroll 8
    for(int jj=0; jj<64; jj++){
      float a0 = a_s[jj][lgrp*2], a1 = a_s[jj][lgrp*2+1];
      const float4 vv = *(const float4*)&v_s[jj][dgrp*4];
      acc0.x+=a0*vv.x; acc0.y+=a0*vv.y; acc0.z+=a0*vv.z; acc0.w+=a0*vv.w;
      acc1.x+=a1*vv.x; acc1.y+=a1*vv.y; acc1.z+=a1*vv.z; acc1.w+=a1*vv.w;
    }
    __syncthreads();
  }
  *(float4*)&fin_s[lgrp*2+0][dgrp*4] = acc0;
  *(float4*)&fin_s[lgrp*2+1][dgrp*4] = acc1;
  __syncthreads();
  for(int it=t; it<32*16; it+=256){
    int l=it>>4, c=it&15;
    cat[(long)(l0+l)*1536 + h*192 + c] = fin_s[l][c];
  }
  for(int it=t; it<32*12; it+=256){
    int l=it/12, p=it%12;
    long gl = l0+l;
    float og0 = fin_s[l][16+p*3+0]-trans[gl*3+0];
    float og1 = fin_s[l][16+p*3+1]-trans[gl*3+1];
    float og2 = fin_s[l][16+p*3+2]-trans[gl*3+2];
    float* crow = cat + gl*1536 + h*192;
    float nrm=0;
    #pragma unroll
    for(int i=0;i<3;i++){
      float v = rot[gl*9+0+i]*og0 + rot[gl*9+3+i]*og1 + rot[gl*9+6+i]*og2;
      crow[16+p*3+i]=v; nrm+=v*v;
    }
    crow[52+p]=sqrtf(nrm+1e-8f);
  }
}

// ---------------- kernel 7: o_pair (z_ln recomputed on the fly) ----
__global__ __launch_bounds__(256) void k_opair(const float* attn, const float* z, const float* murs,
                        const float* sc, const float* bi, const int* ridx, float* cat){
  int l=blockIdx.x, t=threadIdx.x;
  __shared__ float ar[H][NRES];
  for(int it=t; it<H*NRES; it+=256){
    int h=it/NRES, n=it%NRES;
    const float* arow = attn + ((long)h*L+l)*L + n*3;
    ar[h][n]=arow[0]+arow[1]+arow[2];
  }
  __syncthreads();
  int c=t&127, hg=(t>>7)*4;
  int rl=ridx[l];
  float scc=sc[c], bic=bi[c];
  float acc0=0,acc1=0,acc2=0,acc3=0;
  const float* zrow = z + ((long)rl*NRES)*CZ + c;
  const float* mr = murs + (long)rl*NRES*2;
  for(int n=0;n<NRES;n++){
    float zv=(zrow[(long)n*CZ] - mr[n*2])*mr[n*2+1]*scc + bic;
    acc0+=ar[hg+0][n]*zv; acc1+=ar[hg+1][n]*zv;
    acc2+=ar[hg+2][n]*zv; acc3+=ar[hg+3][n]*zv;
  }
  float* crow = cat + (long)l*1536;
  crow[(hg+0)*192+64+c]=acc0; crow[(hg+1)*192+64+c]=acc1;
  crow[(hg+2)*192+64+c]=acc2; crow[(hg+3)*192+64+c]=acc3;
}

// ---------------- kernel 8: final GEMM + bias, tiled ---------------
__global__ __launch_bounds__(256) void k_final(const float* cat, const float* wout, const float* bout, float* out){
  int l0 = blockIdx.x*32, c0 = blockIdx.y*32, t = threadIdx.x;
  __shared__ float a_s[64][33];
  __shared__ __align__(16) float w_s[64][36];
  int tr = t>>3, tc = t&7;       // 32 rows x 8 col-groups(4)
  float4 acc = {0,0,0,0};
  for(int kc=0; kc<24; kc++){
    int k0 = kc*64;
    {
      int row = t>>3, kk0 = (t&7)*8;
      const float4* src = (const float4*)(cat + (long)(l0+row)*1536 + k0 + kk0);
      float4 v0 = src[0], v1 = src[1];
      a_s[kk0+0][row]=v0.x; a_s[kk0+1][row]=v0.y; a_s[kk0+2][row]=v0.z; a_s[kk0+3][row]=v0.w;
      a_s[kk0+4][row]=v1.x; a_s[kk0+5][row]=v1.y; a_s[kk0+6][row]=v1.z; a_s[kk0+7][row]=v1.w;
    }
    #pragma unroll
    for(int kk2=0; kk2<2; kk2++){
      int kk = (t>>3) + 32*kk2;
      *(float4*)&w_s[kk][(t&7)*4] = *(const float4*)(wout + (long)(k0+kk)*256 + c0 + (t&7)*4);
    }
    __syncthreads();
    #pragma unroll 8
    for(int kk=0; kk<64; kk++){
      float a0 = a_s[kk][tr];
      float4 b4 = *(const float4*)&w_s[kk][tc*4];
      acc.x+=a0*b4.x; acc.y+=a0*b4.y; acc.z+=a0*b4.z; acc.w+=a0*b4.w;
    }
    __syncthreads();
  }
  float4 bv = *(const float4*)(bout + c0 + tc*4);
  acc.x+=bv.x; acc.y+=bv.y; acc.z+=bv.z; acc.w+=bv.w;
  *(float4*)(out + (long)(l0+tr)*256 + c0 + tc*4) = acc;
}

extern "C" void kernel_launch(void* const* d_in, const int* in_sizes, int n_in,
                              void* d_out, int out_size, void* d_ws, size_t ws_size,
                              hipStream_t stream) {
  const float* s      = (const float*)d_in[0];
  const float* z      = (const float*)d_in[1];
  const float* rot    = (const float*)d_in[2];
  const float* trans  = (const float*)d_in[3];
  const float* mask   = (const float*)d_in[4];
  const float* lnss   = (const float*)d_in[5];
  const float* lnsb   = (const float*)d_in[6];
  const float* lnzs   = (const float*)d_in[7];
  const float* lnzb   = (const float*)d_in[8];
  const float* wq     = (const float*)d_in[9];
  const float* wk     = (const float*)d_in[10];
  const float* wv     = (const float*)d_in[11];
  const float* wqp    = (const float*)d_in[12];
  const float* wkp    = (const float*)d_in[13];
  const float* wvp    = (const float*)d_in[14];
  const float* wb     = (const float*)d_in[15];
  const float* hws    = (const float*)d_in[16];
  const float* wout   = (const float*)d_in[17];
  const float* bout   = (const float*)d_in[18];
  const int*  ridx    = (const int*)d_in[19];

  float* ws  = (float*)d_ws;
  float* out = (float*)d_out;

  float* sln  = ws + OFF_SLN;
  float* proj = ws + OFF_PROJ;
  float* wpk  = ws + OFF_WPK;
  float* qcat = ws + OFF_QCAT;
  float* kcat = ws + OFF_KCAT;
  float* vcat = ws + OFF_VCAT;
  float* bres = ws + OFF_BRES;
  float* murs = ws + OFF_MURS;
  float* attn = ws + OFF_ATTN;
  float* cat  = ws + OFF_CAT;

  k_packw<<<dim3(256), dim3(256), 0, stream>>>(wq, wk, wv, wqp, wkp, wvp, wpk);
  k_ln_s<<<dim3(L), dim3(CS), 0, stream>>>(s, lnss, lnsb, sln);
  k_proj<<<dim3(18,17), dim3(256), 0, stream>>>(sln, wpk, proj);
  k_ln_z<<<dim3(NRES*NRES/32), dim3(256), 0, stream>>>(z, lnzs, lnzb, wb, murs, bres);
  k_rigid<<<dim3(L), dim3(256), 0, stream>>>(proj, rot, trans, mask, hws, qcat, kcat, vcat);
  k_scores<<<dim3(L/16, H), dim3(256), 0, stream>>>(qcat, kcat, bres, ridx, attn);
  k_av<<<dim3(L/32, H), dim3(256), 0, stream>>>(attn, vcat, rot, trans, cat);
  k_opair<<<dim3(L), dim3(256), 0, stream>>>(attn, z, murs, lnzs, lnzb, ridx, cat);
  k_final<<<dim3(36,8), dim3(256), 0, stream>>>(cat, wout, bout, out);
}

// Round 8
// 401.035 us; speedup vs baseline: 4.6356x; 4.6356x over previous
//
#include <hip/hip_runtime.h>
#include <hip/hip_bf16.h>

#define L 1152
#define NRES 384
#define CS 256
#define CZ 128
#define H 8
#define CH 16
#define PQ 8
#define PV 12
#define PSTR 1088   // padded projection row stride (17*64)

// workspace offsets (in floats)
#define OFF_SLN  0L          // 1152*256      = 294912
#define OFF_PROJ 294912L     // 1152*1088     = 1253376
#define OFF_WPK  1548288L    // 256*1088      = 278528
#define OFF_QCAT 1826816L    // 8*1152*44     = 405504
#define OFF_KCAT 2232320L    // 8*1152*44     = 405504
#define OFF_VCAT 2637824L    // 8*1152*64     = 589824
#define OFF_BRES 3227648L    // 8*147456      = 1179648 (transposed [h][rp])
#define OFF_MURS 4407296L    // 384*384*2     = 294912
#define OFF_ATTN 4702208L    // 8*1152*1152   = 10616832
#define OFF_CAT  15319040L   // 1152*1536     = 1769472
// total fp32: 17088512 floats = 68.4 MB

// ---------------- kernel 1: LayerNorm(s) -> fp32 -------------------
__global__ __launch_bounds__(256) void k_ln_s(const float* s, const float* sc, const float* bi, float* sln){
  int l = blockIdx.x, t = threadIdx.x;
  __shared__ float red[CS];
  float x = s[(long)l*CS + t];
  red[t] = x; __syncthreads();
  for(int st=128; st>0; st>>=1){ if(t<st) red[t]+=red[t+st]; __syncthreads(); }
  float mu = red[0] * (1.f/CS); __syncthreads();
  float d = x - mu;
  red[t] = d*d; __syncthreads();
  for(int st=128; st>0; st>>=1){ if(t<st) red[t]+=red[t+st]; __syncthreads(); }
  float var = red[0]*(1.f/CS);
  sln[(long)l*CS + t] = d*rsqrtf(var + 1e-5f)*sc[t] + bi[t];
}

// ---------------- kernel 1b: pack six weight mats into wpack[256][1088]
__global__ __launch_bounds__(256) void k_packw(const float* wq, const float* wk, const float* wv,
                        const float* wqp, const float* wkp, const float* wvp, float* wpack){
  int k = blockIdx.x, t = threadIdx.x;
  for(int c=t; c<PSTR; c+=256){
    float v;
    if(c<128)        v = wq [(long)k*128 + c];
    else if(c<256)   v = wk [(long)k*128 + c-128];
    else if(c<384)   v = wv [(long)k*128 + c-256];
    else if(c<576)   v = wqp[(long)k*192 + c-384];
    else if(c<768)   v = wkp[(long)k*192 + c-576];
    else if(c<1056)  v = wvp[(long)k*288 + c-768];
    else             v = 0.f;
    wpack[(long)k*PSTR + c] = v;
  }
}

// ---------------- kernel 2: projections as tiled GEMM --------------
__global__ __launch_bounds__(256) void k_proj(const float* sln, const float* wpack, float* proj){
  int l0 = blockIdx.x*64, c0 = blockIdx.y*64, t = threadIdx.x;
  __shared__ float a_s[32][68];
  __shared__ __align__(16) float w_s[32][68];
  int tr = t>>4, tc = t&15;
  float4 acc[4] = {{0,0,0,0},{0,0,0,0},{0,0,0,0},{0,0,0,0}};
  for(int kc=0; kc<8; kc++){
    int k0 = kc*32;
    {
      int row = t>>2, kk0 = (t&3)*8;
      const float4* src = (const float4*)(sln + (long)(l0+row)*256 + k0 + kk0);
      float4 v0 = src[0], v1 = src[1];
      a_s[kk0+0][row]=v0.x; a_s[kk0+1][row]=v0.y; a_s[kk0+2][row]=v0.z; a_s[kk0+3][row]=v0.w;
      a_s[kk0+4][row]=v1.x; a_s[kk0+5][row]=v1.y; a_s[kk0+6][row]=v1.z; a_s[kk0+7][row]=v1.w;
    }
    #pragma unroll
    for(int kk2=0; kk2<2; kk2++){
      int kk = (t>>4) + 16*kk2;
      *(float4*)&w_s[kk][(t&15)*4] = *(const float4*)(wpack + (long)(k0+kk)*PSTR + c0 + (t&15)*4);
    }
    __syncthreads();
    #pragma unroll 8
    for(int kk=0; kk<32; kk++){
      float4 a4 = *(const float4*)&a_s[kk][tr*4];
      float4 b4 = *(const float4*)&w_s[kk][tc*4];
      acc[0].x+=a4.x*b4.x; acc[0].y+=a4.x*b4.y; acc[0].z+=a4.x*b4.z; acc[0].w+=a4.x*b4.w;
      acc[1].x+=a4.y*b4.x; acc[1].y+=a4.y*b4.y; acc[1].z+=a4.y*b4.z; acc[1].w+=a4.y*b4.w;
      acc[2].x+=a4.z*b4.x; acc[2].y+=a4.z*b4.y; acc[2].z+=a4.z*b4.z; acc[2].w+=a4.z*b4.w;
      acc[3].x+=a4.w*b4.x; acc[3].y+=a4.w*b4.y; acc[3].z+=a4.w*b4.z; acc[3].w+=a4.w*b4.w;
    }
    __syncthreads();
  }
  #pragma unroll
  for(int r=0;r<4;r++)
    *(float4*)(proj + (long)(l0 + tr*4 + r)*PSTR + c0 + tc*4) = acc[r];
}

// ---------------- kernel 3: LayerNorm(z) stats + b_res = z_ln @ w_b
__global__ __launch_bounds__(256) void k_ln_z(const float* z, const float* sc, const float* bi,
                       const float* wb, float* murs, float* bres_t){
  int t = threadIdx.x;
  long rp0 = (long)blockIdx.x*32;
  int r = t>>3, part = t&7;
  long rp = rp0 + r;
  __shared__ __align__(16) float swb[8*132];   // [h][c] padded to 132
  __shared__ float SB[8][2];
  const float4* z4 = (const float4*)z;
  float4 x0 = z4[rp*32 + part*4 + 0];
  float4 x1 = z4[rp*32 + part*4 + 1];
  float4 x2 = z4[rp*32 + part*4 + 2];
  float4 x3 = z4[rp*32 + part*4 + 3];
  #pragma unroll
  for(int k2=0;k2<4;k2++){
    int e = t + k2*256; int h = e>>7, c = e&127;
    swb[h*132 + c] = sc[c]*wb[(long)c*8 + h];
  }
  __syncthreads();
  if(t < 64){
    int h = t>>3, seg = t&7;
    float S=0, Bv=0;
    #pragma unroll
    for(int i=0;i<16;i++){
      int c = seg*16+i;
      S  += swb[h*132+c];
      Bv += bi[c]*wb[(long)c*8 + h];
    }
    #pragma unroll
    for(int off=1;off<8;off<<=1){ S += __shfl_xor(S,off,64); Bv += __shfl_xor(Bv,off,64); }
    if(seg==0){ SB[h][0]=S; SB[h][1]=Bv; }
  }
  float s1 = x0.x+x0.y+x0.z+x0.w + x1.x+x1.y+x1.z+x1.w
           + x2.x+x2.y+x2.z+x2.w + x3.x+x3.y+x3.z+x3.w;
  float s2 = x0.x*x0.x+x0.y*x0.y+x0.z*x0.z+x0.w*x0.w
           + x1.x*x1.x+x1.y*x1.y+x1.z*x1.z+x1.w*x1.w
           + x2.x*x2.x+x2.y*x2.y+x2.z*x2.z+x2.w*x2.w
           + x3.x*x3.x+x3.y*x3.y+x3.z*x3.z+x3.w*x3.w;
  #pragma unroll
  for(int off=1;off<8;off<<=1){ s1 += __shfl_xor(s1,off,64); s2 += __shfl_xor(s2,off,64); }
  float mu = s1*(1.f/CZ);
  float var = s2*(1.f/CZ) - mu*mu;
  float rstd = rsqrtf(var + 1e-5f);
  if(part==0){ murs[rp*2]=mu; murs[rp*2+1]=rstd; }
  float acc[8];
  const float4* swb4 = (const float4*)swb;  // 33 float4 per h-row
  #pragma unroll
  for(int h=0;h<8;h++){
    float4 wa = swb4[h*33 + part*4 + 0];
    float4 wbv= swb4[h*33 + part*4 + 1];
    float4 wc = swb4[h*33 + part*4 + 2];
    float4 wd = swb4[h*33 + part*4 + 3];
    acc[h] = x0.x*wa.x + x0.y*wa.y + x0.z*wa.z + x0.w*wa.w
           + x1.x*wbv.x+ x1.y*wbv.y+ x1.z*wbv.z+ x1.w*wbv.w
           + x2.x*wc.x + x2.y*wc.y + x2.z*wc.z + x2.w*wc.w
           + x3.x*wd.x + x3.y*wd.y + x3.z*wd.z + x3.w*wd.w;
  }
  #pragma unroll
  for(int off=1;off<8;off<<=1){
    #pragma unroll
    for(int h=0;h<8;h++) acc[h] += __shfl_xor(acc[h],off,64);
  }
  __syncthreads();
  if(part==0){
    #pragma unroll
    for(int h=0;h<8;h++)
      bres_t[(long)h*147456 + rp] = rstd*(acc[h] - mu*SB[h][0]) + SB[h][1];
  }
}

// ---------------- kernel 4: rigid transforms + score-vector packing
__global__ __launch_bounds__(256) void k_rigid(const float* proj, const float* rot, const float* trans,
                        const float* mask, const float* hws,
                        float* qcat, float* kcat, float* vcat){
  int l = blockIdx.x, t = threadIdx.x;
  __shared__ float R[9], T[3], hwS[8], qgs[192], kgs[192];
  if(t<9) R[t]=rot[(long)l*9+t];
  if(t<3) T[t]=trans[(long)l*3+t];
  if(t>=16 && t<24) hwS[t-16] = log1pf(expf(hws[t-16]))*0.09622504486493764f;
  __syncthreads();
  const float* pr = proj + (long)l*PSTR;
  if(t<128){
    int h=t>>4, c=t&15;
    long base = ((long)h*L + l)*44;
    qcat[base + c] = 0.14433756729740643f * pr[t];
    kcat[base + c] = pr[128+t];
    vcat[((long)h*L + l)*64 + c] = pr[256+t];
  }
  if(t < 192){
    int h=t/24, m=t%24, p=m/3, i=m%3;
    float qa = R[i*3+0]*pr[384+h*24+p*3+0] + R[i*3+1]*pr[384+h*24+p*3+1]
             + R[i*3+2]*pr[384+h*24+p*3+2] + T[i];
    float ka = R[i*3+0]*pr[576+h*24+p*3+0] + R[i*3+1]*pr[576+h*24+p*3+1]
             + R[i*3+2]*pr[576+h*24+p*3+2] + T[i];
    qgs[t]=qa; kgs[t]=ka;
    long base = ((long)h*L + l)*44 + 16 + m;
    qcat[base] = hwS[h]*qa;
    kcat[base] = ka;
  }
  for(int it=t; it<288; it+=256){
    int h=it/36, m=it%36, p=m/3, i=m%3;
    float a = R[i*3+0]*pr[768+h*36+p*3+0] + R[i*3+1]*pr[768+h*36+p*3+1]
            + R[i*3+2]*pr[768+h*36+p*3+2] + T[i];
    vcat[((long)h*L + l)*64 + 16 + m] = a;
  }
  if(t < 96){
    int h=t/12, d=t%12;
    vcat[((long)h*L + l)*64 + 52 + d] = 0.f;
  }
  __syncthreads();
  if(t < 8){
    float qq=0, kk=0;
    #pragma unroll
    for(int m=0;m<24;m++){ qq += qgs[t*24+m]*qgs[t*24+m]; kk += kgs[t*24+m]*kgs[t*24+m]; }
    long base = ((long)t*L + l)*44;
    qcat[base + 40] = -0.5f*hwS[t]*qq;
    kcat[base + 40] = -0.5f*hwS[t]*kk + (mask[l]-1.f)*1e9f;
  }
}

// ---------------- kernel 5a: raw scores, 2D-tiled GEMM (K=40) ------
// grid (36 l-tiles, 18 j-tiles, 8 h); block computes 32l x 64j scores.
// Each thread: 4l x 2j register tile -> 8 accumulators, no spill.
__global__ __launch_bounds__(256) void k_scores(const float* qcat, const float* kcat,
                         const float* bres_t, const int* ridx, float* attn){
  int l0 = blockIdx.x*32, j0 = blockIdx.y*64, h = blockIdx.z;
  int t = threadIdx.x;
  __shared__ __align__(16) float q_s[32*44];
  __shared__ __align__(16) float k_s[64*44];
  __shared__ int rj_s[64];
  {
    const float* srcq = qcat + ((long)h*L + l0)*44;
    for(int i=t; i<32*44; i+=256) q_s[i]=srcq[i];
    const float* srck = kcat + ((long)h*L + j0)*44;
    for(int i=t; i<64*44; i+=256) k_s[i]=srck[i];
    if(t<64) rj_s[t]=ridx[j0+t];
  }
  __syncthreads();
  int a = t>>5;   // row group 0..7
  int b = t&31;   // col group 0..31
  float acc[4][2] = {{0,0},{0,0},{0,0},{0,0}};
  const float4* q4 = (const float4*)q_s;
  const float4* k4 = (const float4*)k_s;
  #pragma unroll
  for(int i=0;i<10;i++){
    float4 kA = k4[(long)b*11 + i];
    float4 kB = k4[(long)(b+32)*11 + i];
    #pragma unroll
    for(int r=0;r<4;r++){
      float4 qv = q4[(long)(a+8*r)*11 + i];
      acc[r][0] += qv.x*kA.x + qv.y*kA.y + qv.z*kA.z + qv.w*kA.w;
      acc[r][1] += qv.x*kB.x + qv.y*kB.y + qv.z*kB.z + qv.w*kB.w;
    }
  }
  float colc0 = k_s[b*44+40], colc1 = k_s[(b+32)*44+40];
  int rj0 = rj_s[b], rj1 = rj_s[b+32];
  const float* bbh = bres_t + (long)h*147456;
  #pragma unroll
  for(int r=0;r<4;r++){
    int row = a+8*r;
    float rowc = q_s[row*44+40];
    int rl = ridx[l0+row];
    const float* bb = bbh + (long)rl*NRES;
    float s0 = acc[r][0] + rowc + colc0 + 0.5773502691896258f*bb[rj0];
    float s1 = acc[r][1] + rowc + colc1 + 0.5773502691896258f*bb[rj1];
    float* arow = attn + ((long)h*L + l0+row)*L + j0;
    arow[b]    = s0;
    arow[b+32] = s1;
  }
}

// ---------------- kernel 5b: in-place row softmax ------------------
// one wave per (h,l) row; 18 elements/lane.
__global__ __launch_bounds__(256) void k_smax(float* attn){
  long row = (long)blockIdx.x*4 + (threadIdx.x>>6);
  int lane = threadIdx.x & 63;
  float* p = attn + row*L;
  float v[18];
  float m=-1e30f;
  #pragma unroll
  for(int i=0;i<18;i++){ v[i]=p[lane + i*64]; m=fmaxf(m,v[i]); }
  #pragma unroll
  for(int off=1;off<64;off<<=1) m=fmaxf(m,__shfl_xor(m,off,64));
  float s=0;
  #pragma unroll
  for(int i=0;i<18;i++){ v[i]=__expf(v[i]-m); s+=v[i]; }
  #pragma unroll
  for(int off=1;off<64;off<<=1) s+=__shfl_xor(s,off,64);
  float inv=1.f/s;
  #pragma unroll
  for(int i=0;i<18;i++) p[lane+i*64]=v[i]*inv;
}

// ---------------- kernel 6: tiled GEMM o|o_pt + epilogue -----------
__global__ __launch_bounds__(256) void k_av(const float* attn, const float* vcat,
                     const float* rot, const float* trans, float* cat){
  int lb = blockIdx.x, h = blockIdx.y, t = threadIdx.x;
  int l0 = lb*32;
  __shared__ float a_s[64][33];
  __shared__ __align__(16) float v_s[64][68];
  __shared__ __align__(16) float fin_s[32][64];
  int lgrp = t>>4, dgrp = t&15;   // 16 x 16
  float4 acc0 = {0,0,0,0}, acc1 = {0,0,0,0};
  const float* abase = attn + ((long)h*L + l0)*L;
  for(int jc=0; jc<18; jc++){
    int j0 = jc*64;
    {
      int al = t>>3, jj0 = (t&7)*8;
      const float4* src = (const float4*)(abase + (long)al*L + j0 + jj0);
      float4 p0 = src[0], p1 = src[1];
      a_s[jj0+0][al]=p0.x; a_s[jj0+1][al]=p0.y; a_s[jj0+2][al]=p0.z; a_s[jj0+3][al]=p0.w;
      a_s[jj0+4][al]=p1.x; a_s[jj0+5][al]=p1.y; a_s[jj0+6][al]=p1.z; a_s[jj0+7][al]=p1.w;
    }
    {
      int jj = t>>2, seg = t&3;
      const float4* src = (const float4*)(vcat + ((long)h*L + j0 + jj)*64 + seg*16);
      float4 q0=src[0], q1=src[1], q2=src[2], q3=src[3];
      float4* dst = (float4*)&v_s[jj][seg*16];
      dst[0]=q0; dst[1]=q1; dst[2]=q2; dst[3]=q3;
    }
    __syncthreads();
    #pragma unroll 8
    for(int jj=0; jj<64; jj++){
      float a0 = a_s[jj][lgrp*2], a1 = a_s[jj][lgrp*2+1];
      const float4 vv = *(const float4*)&v_s[jj][dgrp*4];
      acc0.x+=a0*vv.x; acc0.y+=a0*vv.y; acc0.z+=a0*vv.z; acc0.w+=a0*vv.w;
      acc1.x+=a1*vv.x; acc1.y+=a1*vv.y; acc1.z+=a1*vv.z; acc1.w+=a1*vv.w;
    }
    __syncthreads();
  }
  *(float4*)&fin_s[lgrp*2+0][dgrp*4] = acc0;
  *(float4*)&fin_s[lgrp*2+1][dgrp*4] = acc1;
  __syncthreads();
  for(int it=t; it<32*16; it+=256){
    int l=it>>4, c=it&15;
    cat[(long)(l0+l)*1536 + h*192 + c] = fin_s[l][c];
  }
  for(int it=t; it<32*12; it+=256){
    int l=it/12, p=it%12;
    long gl = l0+l;
    float og0 = fin_s[l][16+p*3+0]-trans[gl*3+0];
    float og1 = fin_s[l][16+p*3+1]-trans[gl*3+1];
    float og2 = fin_s[l][16+p*3+2]-trans[gl*3+2];
    float* crow = cat + gl*1536 + h*192;
    float nrm=0;
    #pragma unroll
    for(int i=0;i<3;i++){
      float v = rot[gl*9+0+i]*og0 + rot[gl*9+3+i]*og1 + rot[gl*9+6+i]*og2;
      crow[16+p*3+i]=v; nrm+=v*v;
    }
    crow[52+p]=sqrtf(nrm+1e-8f);
  }
}

// ---------------- kernel 7: o_pair (z_ln recomputed on the fly) ----
__global__ __launch_bounds__(256) void k_opair(const float* attn, const float* z, const float* murs,
                        const float* sc, const float* bi, const int* ridx, float* cat){
  int l=blockIdx.x, t=threadIdx.x;
  __shared__ float ar[H][NRES];
  for(int it=t; it<H*NRES; it+=256){
    int h=it/NRES, n=it%NRES;
    const float* arow = attn + ((long)h*L+l)*L + n*3;
    ar[h][n]=arow[0]+arow[1]+arow[2];
  }
  __syncthreads();
  int c=t&127, hg=(t>>7)*4;
  int rl=ridx[l];
  float scc=sc[c], bic=bi[c];
  float acc0=0,acc1=0,acc2=0,acc3=0;
  const float* zrow = z + ((long)rl*NRES)*CZ + c;
  const float* mr = murs + (long)rl*NRES*2;
  for(int n=0;n<NRES;n++){
    float zv=(zrow[(long)n*CZ] - mr[n*2])*mr[n*2+1]*scc + bic;
    acc0+=ar[hg+0][n]*zv; acc1+=ar[hg+1][n]*zv;
    acc2+=ar[hg+2][n]*zv; acc3+=ar[hg+3][n]*zv;
  }
  float* crow = cat + (long)l*1536;
  crow[(hg+0)*192+64+c]=acc0; crow[(hg+1)*192+64+c]=acc1;
  crow[(hg+2)*192+64+c]=acc2; crow[(hg+3)*192+64+c]=acc3;
}

// ---------------- kernel 8: final GEMM + bias, tiled ---------------
__global__ __launch_bounds__(256) void k_final(const float* cat, const float* wout, const float* bout, float* out){
  int l0 = blockIdx.x*32, c0 = blockIdx.y*32, t = threadIdx.x;
  __shared__ float a_s[64][33];
  __shared__ __align__(16) float w_s[64][36];
  int tr = t>>3, tc = t&7;       // 32 rows x 8 col-groups(4)
  float4 acc = {0,0,0,0};
  for(int kc=0; kc<24; kc++){
    int k0 = kc*64;
    {
      int row = t>>3, kk0 = (t&7)*8;
      const float4* src = (const float4*)(cat + (long)(l0+row)*1536 + k0 + kk0);
      float4 v0 = src[0], v1 = src[1];
      a_s[kk0+0][row]=v0.x; a_s[kk0+1][row]=v0.y; a_s[kk0+2][row]=v0.z; a_s[kk0+3][row]=v0.w;
      a_s[kk0+4][row]=v1.x; a_s[kk0+5][row]=v1.y; a_s[kk0+6][row]=v1.z; a_s[kk0+7][row]=v1.w;
    }
    #pragma unroll
    for(int kk2=0; kk2<2; kk2++){
      int kk = (t>>3) + 32*kk2;
      *(float4*)&w_s[kk][(t&7)*4] = *(const float4*)(wout + (long)(k0+kk)*256 + c0 + (t&7)*4);
    }
    __syncthreads();
    #pragma unroll 8
    for(int kk=0; kk<64; kk++){
      float a0 = a_s[kk][tr];
      float4 b4 = *(const float4*)&w_s[kk][tc*4];
      acc.x+=a0*b4.x; acc.y+=a0*b4.y; acc.z+=a0*b4.z; acc.w+=a0*b4.w;
    }
    __syncthreads();
  }
  float4 bv = *(const float4*)(bout + c0 + tc*4);
  acc.x+=bv.x; acc.y+=bv.y; acc.z+=bv.z; acc.w+=bv.w;
  *(float4*)(out + (long)(l0+tr)*256 + c0 + tc*4) = acc;
}

extern "C" void kernel_launch(void* const* d_in, const int* in_sizes, int n_in,
                              void* d_out, int out_size, void* d_ws, size_t ws_size,
                              hipStream_t stream) {
  const float* s      = (const float*)d_in[0];
  const float* z      = (const float*)d_in[1];
  const float* rot    = (const float*)d_in[2];
  const float* trans  = (const float*)d_in[3];
  const float* mask   = (const float*)d_in[4];
  const float* lnss   = (const float*)d_in[5];
  const float* lnsb   = (const float*)d_in[6];
  const float* lnzs   = (const float*)d_in[7];
  const float* lnzb   = (const float*)d_in[8];
  const float* wq     = (const float*)d_in[9];
  const float* wk     = (const float*)d_in[10];
  const float* wv     = (const float*)d_in[11];
  const float* wqp    = (const float*)d_in[12];
  const float* wkp    = (const float*)d_in[13];
  const float* wvp    = (const float*)d_in[14];
  const float* wb     = (const float*)d_in[15];
  const float* hws    = (const float*)d_in[16];
  const float* wout   = (const float*)d_in[17];
  const float* bout   = (const float*)d_in[18];
  const int*  ridx    = (const int*)d_in[19];

  float* ws  = (float*)d_ws;
  float* out = (float*)d_out;

  float* sln  = ws + OFF_SLN;
  float* proj = ws + OFF_PROJ;
  float* wpk  = ws + OFF_WPK;
  float* qcat = ws + OFF_QCAT;
  float* kcat = ws + OFF_KCAT;
  float* vcat = ws + OFF_VCAT;
  float* bres = ws + OFF_BRES;
  float* murs = ws + OFF_MURS;
  float* attn = ws + OFF_ATTN;
  float* cat  = ws + OFF_CAT;

  k_packw<<<dim3(256), dim3(256), 0, stream>>>(wq, wk, wv, wqp, wkp, wvp, wpk);
  k_ln_s<<<dim3(L), dim3(CS), 0, stream>>>(s, lnss, lnsb, sln);
  k_proj<<<dim3(18,17), dim3(256), 0, stream>>>(sln, wpk, proj);
  k_ln_z<<<dim3(NRES*NRES/32), dim3(256), 0, stream>>>(z, lnzs, lnzb, wb, murs, bres);
  k_rigid<<<dim3(L), dim3(256), 0, stream>>>(proj, rot, trans, mask, hws, qcat, kcat, vcat);
  k_scores<<<dim3(L/32, L/64, H), dim3(256), 0, stream>>>(qcat, kcat, bres, ridx, attn);
  k_smax<<<dim3(H*L/4), dim3(256), 0, stream>>>(attn);
  k_av<<<dim3(L/32, H), dim3(256), 0, stream>>>(attn, vcat, rot, trans, cat);
  k_opair<<<dim3(L), dim3(256), 0, stream>>>(attn, z, murs, lnzs, lnzb, ridx, cat);
  k_final<<<dim3(36,8), dim3(256), 0, stream>>>(cat, wout, bout, out);
}

// Round 9
// 356.345 us; speedup vs baseline: 5.2170x; 1.1254x over previous
//
#include <hip/hip_runtime.h>
#include <hip/hip_bf16.h>

#define L 1152
#define NRES 384
#define CS 256
#define CZ 128
#define H 8
#define CH 16
#define PQ 8
#define PV 12
#define PSTR 1088   // padded projection row stride (17*64)

// workspace offsets (in floats)
#define OFF_SLN  0L          // 1152*256      = 294912
#define OFF_PROJ 294912L     // 1152*1088     = 1253376
#define OFF_WPK  1548288L    // 256*1088      = 278528
#define OFF_QCAT 1826816L    // 8*1152*44     = 405504
#define OFF_KCAT 2232320L    // 8*1152*44     = 405504
#define OFF_VCAT 2637824L    // 8*1152*64     = 589824
#define OFF_BRES 3227648L    // 8*147456      = 1179648 (transposed [h][rp])
#define OFF_MURS 4407296L    // 384*384*2     = 294912
#define OFF_ATTN 4702208L    // 8*1152*1152   = 10616832
#define OFF_CAT  15319040L   // 1152*1536     = 1769472
#define OFF_PCAT 17088512L   // 4*1152*256    = 1179648
// total fp32: 18268160 floats = 73.1 MB

// ---------------- kernel 1: LayerNorm(s) -> fp32 -------------------
__global__ __launch_bounds__(256) void k_ln_s(const float* s, const float* sc, const float* bi, float* sln){
  int l = blockIdx.x, t = threadIdx.x;
  __shared__ float red[CS];
  float x = s[(long)l*CS + t];
  red[t] = x; __syncthreads();
  for(int st=128; st>0; st>>=1){ if(t<st) red[t]+=red[t+st]; __syncthreads(); }
  float mu = red[0] * (1.f/CS); __syncthreads();
  float d = x - mu;
  red[t] = d*d; __syncthreads();
  for(int st=128; st>0; st>>=1){ if(t<st) red[t]+=red[t+st]; __syncthreads(); }
  float var = red[0]*(1.f/CS);
  sln[(long)l*CS + t] = d*rsqrtf(var + 1e-5f)*sc[t] + bi[t];
}

// ---------------- kernel 1b: pack six weight mats into wpack[256][1088]
__global__ __launch_bounds__(256) void k_packw(const float* wq, const float* wk, const float* wv,
                        const float* wqp, const float* wkp, const float* wvp, float* wpack){
  int k = blockIdx.x, t = threadIdx.x;
  for(int c=t; c<PSTR; c+=256){
    float v;
    if(c<128)        v = wq [(long)k*128 + c];
    else if(c<256)   v = wk [(long)k*128 + c-128];
    else if(c<384)   v = wv [(long)k*128 + c-256];
    else if(c<576)   v = wqp[(long)k*192 + c-384];
    else if(c<768)   v = wkp[(long)k*192 + c-576];
    else if(c<1056)  v = wvp[(long)k*288 + c-768];
    else             v = 0.f;
    wpack[(long)k*PSTR + c] = v;
  }
}

// ---------------- kernel 2: projections as tiled GEMM --------------
__global__ __launch_bounds__(256) void k_proj(const float* sln, const float* wpack, float* proj){
  int l0 = blockIdx.x*64, c0 = blockIdx.y*64, t = threadIdx.x;
  __shared__ float a_s[32][68];
  __shared__ __align__(16) float w_s[32][68];
  int tr = t>>4, tc = t&15;
  float4 acc[4] = {{0,0,0,0},{0,0,0,0},{0,0,0,0},{0,0,0,0}};
  for(int kc=0; kc<8; kc++){
    int k0 = kc*32;
    {
      int row = t>>2, kk0 = (t&3)*8;
      const float4* src = (const float4*)(sln + (long)(l0+row)*256 + k0 + kk0);
      float4 v0 = src[0], v1 = src[1];
      a_s[kk0+0][row]=v0.x; a_s[kk0+1][row]=v0.y; a_s[kk0+2][row]=v0.z; a_s[kk0+3][row]=v0.w;
      a_s[kk0+4][row]=v1.x; a_s[kk0+5][row]=v1.y; a_s[kk0+6][row]=v1.z; a_s[kk0+7][row]=v1.w;
    }
    #pragma unroll
    for(int kk2=0; kk2<2; kk2++){
      int kk = (t>>4) + 16*kk2;
      *(float4*)&w_s[kk][(t&15)*4] = *(const float4*)(wpack + (long)(k0+kk)*PSTR + c0 + (t&15)*4);
    }
    __syncthreads();
    #pragma unroll 8
    for(int kk=0; kk<32; kk++){
      float4 a4 = *(const float4*)&a_s[kk][tr*4];
      float4 b4 = *(const float4*)&w_s[kk][tc*4];
      acc[0].x+=a4.x*b4.x; acc[0].y+=a4.x*b4.y; acc[0].z+=a4.x*b4.z; acc[0].w+=a4.x*b4.w;
      acc[1].x+=a4.y*b4.x; acc[1].y+=a4.y*b4.y; acc[1].z+=a4.y*b4.z; acc[1].w+=a4.y*b4.w;
      acc[2].x+=a4.z*b4.x; acc[2].y+=a4.z*b4.y; acc[2].z+=a4.z*b4.z; acc[2].w+=a4.z*b4.w;
      acc[3].x+=a4.w*b4.x; acc[3].y+=a4.w*b4.y; acc[3].z+=a4.w*b4.z; acc[3].w+=a4.w*b4.w;
    }
    __syncthreads();
  }
  #pragma unroll
  for(int r=0;r<4;r++)
    *(float4*)(proj + (long)(l0 + tr*4 + r)*PSTR + c0 + tc*4) = acc[r];
}

// ---------------- kernel 3: LayerNorm(z) stats + b_res = z_ln @ w_b
__global__ __launch_bounds__(256) void k_ln_z(const float* z, const float* sc, const float* bi,
                       const float* wb, float* murs, float* bres_t){
  int t = threadIdx.x;
  long rp0 = (long)blockIdx.x*32;
  int r = t>>3, part = t&7;
  long rp = rp0 + r;
  __shared__ __align__(16) float swb[8*132];   // [h][c] padded to 132
  __shared__ float SB[8][2];
  const float4* z4 = (const float4*)z;
  float4 x0 = z4[rp*32 + part*4 + 0];
  float4 x1 = z4[rp*32 + part*4 + 1];
  float4 x2 = z4[rp*32 + part*4 + 2];
  float4 x3 = z4[rp*32 + part*4 + 3];
  #pragma unroll
  for(int k2=0;k2<4;k2++){
    int e = t + k2*256; int h = e>>7, c = e&127;
    swb[h*132 + c] = sc[c]*wb[(long)c*8 + h];
  }
  __syncthreads();
  if(t < 64){
    int h = t>>3, seg = t&7;
    float S=0, Bv=0;
    #pragma unroll
    for(int i=0;i<16;i++){
      int c = seg*16+i;
      S  += swb[h*132+c];
      Bv += bi[c]*wb[(long)c*8 + h];
    }
    #pragma unroll
    for(int off=1;off<8;off<<=1){ S += __shfl_xor(S,off,64); Bv += __shfl_xor(Bv,off,64); }
    if(seg==0){ SB[h][0]=S; SB[h][1]=Bv; }
  }
  float s1 = x0.x+x0.y+x0.z+x0.w + x1.x+x1.y+x1.z+x1.w
           + x2.x+x2.y+x2.z+x2.w + x3.x+x3.y+x3.z+x3.w;
  float s2 = x0.x*x0.x+x0.y*x0.y+x0.z*x0.z+x0.w*x0.w
           + x1.x*x1.x+x1.y*x1.y+x1.z*x1.z+x1.w*x1.w
           + x2.x*x2.x+x2.y*x2.y+x2.z*x2.z+x2.w*x2.w
           + x3.x*x3.x+x3.y*x3.y+x3.z*x3.z+x3.w*x3.w;
  #pragma unroll
  for(int off=1;off<8;off<<=1){ s1 += __shfl_xor(s1,off,64); s2 += __shfl_xor(s2,off,64); }
  float mu = s1*(1.f/CZ);
  float var = s2*(1.f/CZ) - mu*mu;
  float rstd = rsqrtf(var + 1e-5f);
  if(part==0){ murs[rp*2]=mu; murs[rp*2+1]=rstd; }
  float acc[8];
  const float4* swb4 = (const float4*)swb;  // 33 float4 per h-row
  #pragma unroll
  for(int h=0;h<8;h++){
    float4 wa = swb4[h*33 + part*4 + 0];
    float4 wbv= swb4[h*33 + part*4 + 1];
    float4 wc = swb4[h*33 + part*4 + 2];
    float4 wd = swb4[h*33 + part*4 + 3];
    acc[h] = x0.x*wa.x + x0.y*wa.y + x0.z*wa.z + x0.w*wa.w
           + x1.x*wbv.x+ x1.y*wbv.y+ x1.z*wbv.z+ x1.w*wbv.w
           + x2.x*wc.x + x2.y*wc.y + x2.z*wc.z + x2.w*wc.w
           + x3.x*wd.x + x3.y*wd.y + x3.z*wd.z + x3.w*wd.w;
  }
  #pragma unroll
  for(int off=1;off<8;off<<=1){
    #pragma unroll
    for(int h=0;h<8;h++) acc[h] += __shfl_xor(acc[h],off,64);
  }
  __syncthreads();
  if(part==0){
    #pragma unroll
    for(int h=0;h<8;h++)
      bres_t[(long)h*147456 + rp] = rstd*(acc[h] - mu*SB[h][0]) + SB[h][1];
  }
}

// ---------------- kernel 4: rigid transforms + score-vector packing
__global__ __launch_bounds__(256) void k_rigid(const float* proj, const float* rot, const float* trans,
                        const float* mask, const float* hws,
                        float* qcat, float* kcat, float* vcat){
  int l = blockIdx.x, t = threadIdx.x;
  __shared__ float R[9], T[3], hwS[8], qgs[192], kgs[192];
  if(t<9) R[t]=rot[(long)l*9+t];
  if(t<3) T[t]=trans[(long)l*3+t];
  if(t>=16 && t<24) hwS[t-16] = log1pf(expf(hws[t-16]))*0.09622504486493764f;
  __syncthreads();
  const float* pr = proj + (long)l*PSTR;
  if(t<128){
    int h=t>>4, c=t&15;
    long base = ((long)h*L + l)*44;
    qcat[base + c] = 0.14433756729740643f * pr[t];
    kcat[base + c] = pr[128+t];
    vcat[((long)h*L + l)*64 + c] = pr[256+t];
  }
  if(t < 192){
    int h=t/24, m=t%24, p=m/3, i=m%3;
    float qa = R[i*3+0]*pr[384+h*24+p*3+0] + R[i*3+1]*pr[384+h*24+p*3+1]
             + R[i*3+2]*pr[384+h*24+p*3+2] + T[i];
    float ka = R[i*3+0]*pr[576+h*24+p*3+0] + R[i*3+1]*pr[576+h*24+p*3+1]
             + R[i*3+2]*pr[576+h*24+p*3+2] + T[i];
    qgs[t]=qa; kgs[t]=ka;
    long base = ((long)h*L + l)*44 + 16 + m;
    qcat[base] = hwS[h]*qa;
    kcat[base] = ka;
  }
  for(int it=t; it<288; it+=256){
    int h=it/36, m=it%36, p=m/3, i=m%3;
    float a = R[i*3+0]*pr[768+h*36+p*3+0] + R[i*3+1]*pr[768+h*36+p*3+1]
            + R[i*3+2]*pr[768+h*36+p*3+2] + T[i];
    vcat[((long)h*L + l)*64 + 16 + m] = a;
  }
  if(t < 96){
    int h=t/12, d=t%12;
    vcat[((long)h*L + l)*64 + 52 + d] = 0.f;
  }
  __syncthreads();
  if(t < 8){
    float qq=0, kk=0;
    #pragma unroll
    for(int m=0;m<24;m++){ qq += qgs[t*24+m]*qgs[t*24+m]; kk += kgs[t*24+m]*kgs[t*24+m]; }
    long base = ((long)t*L + l)*44;
    qcat[base + 40] = -0.5f*hwS[t]*qq;
    kcat[base + 40] = -0.5f*hwS[t]*kk + (mask[l]-1.f)*1e9f;
  }
}

// ---------------- kernel 5a: raw scores, 2D-tiled GEMM (K=40) ------
__global__ __launch_bounds__(256) void k_scores(const float* qcat, const float* kcat,
                         const float* bres_t, const int* ridx, float* attn){
  int l0 = blockIdx.x*32, j0 = blockIdx.y*64, h = blockIdx.z;
  int t = threadIdx.x;
  __shared__ __align__(16) float q_s[32*44];
  __shared__ __align__(16) float k_s[64*44];
  __shared__ int rj_s[64];
  {
    const float* srcq = qcat + ((long)h*L + l0)*44;
    for(int i=t; i<32*44; i+=256) q_s[i]=srcq[i];
    const float* srck = kcat + ((long)h*L + j0)*44;
    for(int i=t; i<64*44; i+=256) k_s[i]=srck[i];
    if(t<64) rj_s[t]=ridx[j0+t];
  }
  __syncthreads();
  int a = t>>5;   // row group 0..7
  int b = t&31;   // col group 0..31
  float acc[4][2] = {{0,0},{0,0},{0,0},{0,0}};
  const float4* q4 = (const float4*)q_s;
  const float4* k4 = (const float4*)k_s;
  #pragma unroll
  for(int i=0;i<10;i++){
    float4 kA = k4[(long)b*11 + i];
    float4 kB = k4[(long)(b+32)*11 + i];
    #pragma unroll
    for(int r=0;r<4;r++){
      float4 qv = q4[(long)(a+8*r)*11 + i];
      acc[r][0] += qv.x*kA.x + qv.y*kA.y + qv.z*kA.z + qv.w*kA.w;
      acc[r][1] += qv.x*kB.x + qv.y*kB.y + qv.z*kB.z + qv.w*kB.w;
    }
  }
  float colc0 = k_s[b*44+40], colc1 = k_s[(b+32)*44+40];
  int rj0 = rj_s[b], rj1 = rj_s[b+32];
  const float* bbh = bres_t + (long)h*147456;
  #pragma unroll
  for(int r=0;r<4;r++){
    int row = a+8*r;
    float rowc = q_s[row*44+40];
    int rl = ridx[l0+row];
    const float* bb = bbh + (long)rl*NRES;
    float s0 = acc[r][0] + rowc + colc0 + 0.5773502691896258f*bb[rj0];
    float s1 = acc[r][1] + rowc + colc1 + 0.5773502691896258f*bb[rj1];
    float* arow = attn + ((long)h*L + l0+row)*L + j0;
    arow[b]    = s0;
    arow[b+32] = s1;
  }
}

// ---------------- kernel 5b: in-place row softmax ------------------
__global__ __launch_bounds__(256) void k_smax(float* attn){
  long row = (long)blockIdx.x*4 + (threadIdx.x>>6);
  int lane = threadIdx.x & 63;
  float* p = attn + row*L;
  float v[18];
  float m=-1e30f;
  #pragma unroll
  for(int i=0;i<18;i++){ v[i]=p[lane + i*64]; m=fmaxf(m,v[i]); }
  #pragma unroll
  for(int off=1;off<64;off<<=1) m=fmaxf(m,__shfl_xor(m,off,64));
  float s=0;
  #pragma unroll
  for(int i=0;i<18;i++){ v[i]=__expf(v[i]-m); s+=v[i]; }
  #pragma unroll
  for(int off=1;off<64;off<<=1) s+=__shfl_xor(s,off,64);
  float inv=1.f/s;
  #pragma unroll
  for(int i=0;i<18;i++) p[lane+i*64]=v[i]*inv;
}

// ---------------- kernel 6: tiled GEMM o|o_pt + epilogue -----------
__global__ __launch_bounds__(256) void k_av(const float* attn, const float* vcat,
                     const float* rot, const float* trans, float* cat){
  int lb = blockIdx.x, h = blockIdx.y, t = threadIdx.x;
  int l0 = lb*32;
  __shared__ float a_s[64][33];
  __shared__ __align__(16) float v_s[64][68];
  __shared__ __align__(16) float fin_s[32][64];
  int lgrp = t>>4, dgrp = t&15;   // 16 x 16
  float4 acc0 = {0,0,0,0}, acc1 = {0,0,0,0};
  const float* abase = attn + ((long)h*L + l0)*L;
  for(int jc=0; jc<18; jc++){
    int j0 = jc*64;
    {
      int al = t>>3, jj0 = (t&7)*8;
      const float4* src = (const float4*)(abase + (long)al*L + j0 + jj0);
      float4 p0 = src[0], p1 = src[1];
      a_s[jj0+0][al]=p0.x; a_s[jj0+1][al]=p0.y; a_s[jj0+2][al]=p0.z; a_s[jj0+3][al]=p0.w;
      a_s[jj0+4][al]=p1.x; a_s[jj0+5][al]=p1.y; a_s[jj0+6][al]=p1.z; a_s[jj0+7][al]=p1.w;
    }
    {
      int jj = t>>2, seg = t&3;
      const float4* src = (const float4*)(vcat + ((long)h*L + j0 + jj)*64 + seg*16);
      float4 q0=src[0], q1=src[1], q2=src[2], q3=src[3];
      float4* dst = (float4*)&v_s[jj][seg*16];
      dst[0]=q0; dst[1]=q1; dst[2]=q2; dst[3]=q3;
    }
    __syncthreads();
    #pragma unroll 8
    for(int jj=0; jj<64; jj++){
      float a0 = a_s[jj][lgrp*2], a1 = a_s[jj][lgrp*2+1];
      const float4 vv = *(const float4*)&v_s[jj][dgrp*4];
      acc0.x+=a0*vv.x; acc0.y+=a0*vv.y; acc0.z+=a0*vv.z; acc0.w+=a0*vv.w;
      acc1.x+=a1*vv.x; acc1.y+=a1*vv.y; acc1.z+=a1*vv.z; acc1.w+=a1*vv.w;
    }
    __syncthreads();
  }
  *(float4*)&fin_s[lgrp*2+0][dgrp*4] = acc0;
  *(float4*)&fin_s[lgrp*2+1][dgrp*4] = acc1;
  __syncthreads();
  for(int it=t; it<32*16; it+=256){
    int l=it>>4, c=it&15;
    cat[(long)(l0+l)*1536 + h*192 + c] = fin_s[l][c];
  }
  for(int it=t; it<32*12; it+=256){
    int l=it/12, p=it%12;
    long gl = l0+l;
    float og0 = fin_s[l][16+p*3+0]-trans[gl*3+0];
    float og1 = fin_s[l][16+p*3+1]-trans[gl*3+1];
    float og2 = fin_s[l][16+p*3+2]-trans[gl*3+2];
    float* crow = cat + gl*1536 + h*192;
    float nrm=0;
    #pragma unroll
    for(int i=0;i<3;i++){
      float v = rot[gl*9+0+i]*og0 + rot[gl*9+3+i]*og1 + rot[gl*9+6+i]*og2;
      crow[16+p*3+i]=v; nrm+=v*v;
    }
    crow[52+p]=sqrtf(nrm+1e-8f);
  }
}

// ---------------- kernel 7: o_pair, trio-fused (3 rigids per residue)
__global__ __launch_bounds__(256) void k_opair(const float* attn, const float* z, const float* murs,
                        const float* sc, const float* bi, const int* ridx, float* cat){
  int r=blockIdx.x, t=threadIdx.x;
  __shared__ __align__(16) float ar[3][H][NRES];   // 36 KB
  __shared__ __align__(16) float mrs[NRES*2];
  int rl = ridx[r*3];
  for(int it=t; it<3*H*NRES; it+=256){
    int lo = it/(H*NRES);
    int rem = it - lo*(H*NRES);
    int h = rem/NRES, n = rem - h*NRES;
    const float* arow = attn + ((long)h*L + r*3+lo)*L + n*3;
    ar[lo][h][n]=arow[0]+arow[1]+arow[2];
  }
  for(int i=t;i<NRES*2;i+=256) mrs[i]=murs[(long)rl*NRES*2 + i];
  __syncthreads();
  int tc=t&63, th=t>>6;
  int c0=tc*2, h0=th*2;
  float sc0=sc[c0], sc1=sc[c0+1], bi0=bi[c0], bi1=bi[c0+1];
  float acc[3][2][2]={};
  const float* zbase = z + ((long)rl*NRES)*CZ + c0;
  for(int n=0;n<NRES;n+=2){
    float4 mr4 = *(const float4*)&mrs[n*2];   // mu0,rs0,mu1,rs1
    float2 z0 = *(const float2*)(zbase + (long)n*CZ);
    float2 z1 = *(const float2*)(zbase + (long)(n+1)*CZ);
    float zv00 = (z0.x - mr4.x)*mr4.y*sc0 + bi0;
    float zv01 = (z0.y - mr4.x)*mr4.y*sc1 + bi1;
    float zv10 = (z1.x - mr4.z)*mr4.w*sc0 + bi0;
    float zv11 = (z1.y - mr4.z)*mr4.w*sc1 + bi1;
    #pragma unroll
    for(int lo=0;lo<3;lo++){
      #pragma unroll
      for(int hp=0;hp<2;hp++){
        float2 a2 = *(const float2*)&ar[lo][h0+hp][n];
        acc[lo][hp][0] += a2.x*zv00 + a2.y*zv10;
        acc[lo][hp][1] += a2.x*zv01 + a2.y*zv11;
      }
    }
  }
  #pragma unroll
  for(int lo=0;lo<3;lo++){
    float* crow = cat + (long)(r*3+lo)*1536;
    #pragma unroll
    for(int hp=0;hp<2;hp++){
      crow[(h0+hp)*192+64+c0]   = acc[lo][hp][0];
      crow[(h0+hp)*192+64+c0+1] = acc[lo][hp][1];
    }
  }
}

// ---------------- kernel 8a: final GEMM, split-K x4 ----------------
// grid (36, 8, 4); block: 32l x 32c, K-range kp*384..+384.
__global__ __launch_bounds__(256) void k_final(const float* cat, const float* wout, float* pcat){
  int l0 = blockIdx.x*32, c0 = blockIdx.y*32, kp = blockIdx.z, t = threadIdx.x;
  __shared__ float a_s[64][33];
  __shared__ __align__(16) float w_s[64][36];
  int tr = t>>3, tc = t&7;
  float4 acc = {0,0,0,0};
  for(int kc=0; kc<6; kc++){
    int k0 = kp*384 + kc*64;
    {
      int row = t>>3, kk0 = (t&7)*8;
      const float4* src = (const float4*)(cat + (long)(l0+row)*1536 + k0 + kk0);
      float4 v0 = src[0], v1 = src[1];
      a_s[kk0+0][row]=v0.x; a_s[kk0+1][row]=v0.y; a_s[kk0+2][row]=v0.z; a_s[kk0+3][row]=v0.w;
      a_s[kk0+4][row]=v1.x; a_s[kk0+5][row]=v1.y; a_s[kk0+6][row]=v1.z; a_s[kk0+7][row]=v1.w;
    }
    #pragma unroll
    for(int kk2=0; kk2<2; kk2++){
      int kk = (t>>3) + 32*kk2;
      *(float4*)&w_s[kk][(t&7)*4] = *(const float4*)(wout + (long)(k0+kk)*256 + c0 + (t&7)*4);
    }
    __syncthreads();
    #pragma unroll 8
    for(int kk=0; kk<64; kk++){
      float a0 = a_s[kk][tr];
      float4 b4 = *(const float4*)&w_s[kk][tc*4];
      acc.x+=a0*b4.x; acc.y+=a0*b4.y; acc.z+=a0*b4.z; acc.w+=a0*b4.w;
    }
    __syncthreads();
  }
  *(float4*)(pcat + ((long)kp*L + l0+tr)*256 + c0 + tc*4) = acc;
}

// ---------------- kernel 8b: reduce partials + bias ----------------
__global__ __launch_bounds__(256) void k_redout(const float* pcat, const float* bout, float* out){
  int i = blockIdx.x*256 + threadIdx.x;    // float4 index over 73728
  const float4* p = (const float4*)pcat;
  float4 a = p[i], b = p[i+73728], c = p[i+147456], d = p[i+221184];
  float4 bv = ((const float4*)bout)[i&63];
  float4 r;
  r.x = a.x+b.x+c.x+d.x+bv.x;
  r.y = a.y+b.y+c.y+d.y+bv.y;
  r.z = a.z+b.z+c.z+d.z+bv.z;
  r.w = a.w+b.w+c.w+d.w+bv.w;
  ((float4*)out)[i] = r;
}

extern "C" void kernel_launch(void* const* d_in, const int* in_sizes, int n_in,
                              void* d_out, int out_size, void* d_ws, size_t ws_size,
                              hipStream_t stream) {
  const float* s      = (const float*)d_in[0];
  const float* z      = (const float*)d_in[1];
  const float* rot    = (const float*)d_in[2];
  const float* trans  = (const float*)d_in[3];
  const float* mask   = (const float*)d_in[4];
  const float* lnss   = (const float*)d_in[5];
  const float* lnsb   = (const float*)d_in[6];
  const float* lnzs   = (const float*)d_in[7];
  const float* lnzb   = (const float*)d_in[8];
  const float* wq     = (const float*)d_in[9];
  const float* wk     = (const float*)d_in[10];
  const float* wv     = (const float*)d_in[11];
  const float* wqp    = (const float*)d_in[12];
  const float* wkp    = (const float*)d_in[13];
  const float* wvp    = (const float*)d_in[14];
  const float* wb     = (const float*)d_in[15];
  const float* hws    = (const float*)d_in[16];
  const float* wout   = (const float*)d_in[17];
  const float* bout   = (const float*)d_in[18];
  const int*  ridx    = (const int*)d_in[19];

  float* ws  = (float*)d_ws;
  float* out = (float*)d_out;

  float* sln  = ws + OFF_SLN;
  float* proj = ws + OFF_PROJ;
  float* wpk  = ws + OFF_WPK;
  float* qcat = ws + OFF_QCAT;
  float* kcat = ws + OFF_KCAT;
  float* vcat = ws + OFF_VCAT;
  float* bres = ws + OFF_BRES;
  float* murs = ws + OFF_MURS;
  float* attn = ws + OFF_ATTN;
  float* cat  = ws + OFF_CAT;
  float* pcat = ws + OFF_PCAT;

  k_packw<<<dim3(256), dim3(256), 0, stream>>>(wq, wk, wv, wqp, wkp, wvp, wpk);
  k_ln_s<<<dim3(L), dim3(CS), 0, stream>>>(s, lnss, lnsb, sln);
  k_proj<<<dim3(18,17), dim3(256), 0, stream>>>(sln, wpk, proj);
  k_ln_z<<<dim3(NRES*NRES/32), dim3(256), 0, stream>>>(z, lnzs, lnzb, wb, murs, bres);
  k_rigid<<<dim3(L), dim3(256), 0, stream>>>(proj, rot, trans, mask, hws, qcat, kcat, vcat);
  k_scores<<<dim3(L/32, L/64, H), dim3(256), 0, stream>>>(qcat, kcat, bres, ridx, attn);
  k_smax<<<dim3(H*L/4), dim3(256), 0, stream>>>(attn);
  k_av<<<dim3(L/32, H), dim3(256), 0, stream>>>(attn, vcat, rot, trans, cat);
  k_opair<<<dim3(NRES), dim3(256), 0, stream>>>(attn, z, murs, lnzs, lnzb, ridx, cat);
  k_final<<<dim3(36,8,4), dim3(256), 0, stream>>>(cat, wout, pcat);
  k_redout<<<dim3(288), dim3(256), 0, stream>>>(pcat, bout, out);
}

// Round 10
// 338.839 us; speedup vs baseline: 5.4865x; 1.0517x over previous
//
#include <hip/hip_runtime.h>
#include <hip/hip_bf16.h>

#define L 1152
#define NRES 384
#define CS 256
#define CZ 128
#define H 8
#define CH 16
#define PQ 8
#define PV 12
#define PSTR 1088   // padded projection row stride (17*64)

// workspace offsets (in floats)
#define OFF_SLN  0L          // 1152*256      = 294912
#define OFF_PROJ 294912L     // 1152*1088     = 1253376
#define OFF_WPK  1548288L    // 256*1088      = 278528
#define OFF_QCAT 1826816L    // 8*1152*44     = 405504
#define OFF_KCAT 2232320L    // 8*1152*44     = 405504
#define OFF_VCAT 2637824L    // 8*1152*64     = 589824
#define OFF_BRES 3227648L    // 8*147456      = 1179648 (transposed [h][rp])
#define OFF_MURS 4407296L    // 384*384*2     = 294912
#define OFF_ATTN 4702208L    // 8*1152*1152   = 10616832
#define OFF_CAT  15319040L   // 1152*1536     = 1769472
#define OFF_PCAT 17088512L   // 4*1152*256    = 1179648
#define OFF_RSTAT 18268160L  // 9216*2        = 18432
// pav (3*8*1152*64 = 1769472) aliases OFF_SLN..OFF_QCAT (dead after k_rigid)
#define OFF_PAV  0L
// total fp32: 18286592 floats = 73.1 MB

// ---------------- kernel 1: LayerNorm(s) -> fp32 -------------------
__global__ __launch_bounds__(256) void k_ln_s(const float* s, const float* sc, const float* bi, float* sln){
  int l = blockIdx.x, t = threadIdx.x;
  __shared__ float red[CS];
  float x = s[(long)l*CS + t];
  red[t] = x; __syncthreads();
  for(int st=128; st>0; st>>=1){ if(t<st) red[t]+=red[t+st]; __syncthreads(); }
  float mu = red[0] * (1.f/CS); __syncthreads();
  float d = x - mu;
  red[t] = d*d; __syncthreads();
  for(int st=128; st>0; st>>=1){ if(t<st) red[t]+=red[t+st]; __syncthreads(); }
  float var = red[0]*(1.f/CS);
  sln[(long)l*CS + t] = d*rsqrtf(var + 1e-5f)*sc[t] + bi[t];
}

// ---------------- kernel 1b: pack six weight mats into wpack[256][1088]
__global__ __launch_bounds__(256) void k_packw(const float* wq, const float* wk, const float* wv,
                        const float* wqp, const float* wkp, const float* wvp, float* wpack){
  int k = blockIdx.x, t = threadIdx.x;
  for(int c=t; c<PSTR; c+=256){
    float v;
    if(c<128)        v = wq [(long)k*128 + c];
    else if(c<256)   v = wk [(long)k*128 + c-128];
    else if(c<384)   v = wv [(long)k*128 + c-256];
    else if(c<576)   v = wqp[(long)k*192 + c-384];
    else if(c<768)   v = wkp[(long)k*192 + c-576];
    else if(c<1056)  v = wvp[(long)k*288 + c-768];
    else             v = 0.f;
    wpack[(long)k*PSTR + c] = v;
  }
}

// ---------------- kernel 2: projections as tiled GEMM --------------
__global__ __launch_bounds__(256) void k_proj(const float* sln, const float* wpack, float* proj){
  int l0 = blockIdx.x*64, c0 = blockIdx.y*64, t = threadIdx.x;
  __shared__ float a_s[32][68];
  __shared__ __align__(16) float w_s[32][68];
  int tr = t>>4, tc = t&15;
  float4 acc[4] = {{0,0,0,0},{0,0,0,0},{0,0,0,0},{0,0,0,0}};
  for(int kc=0; kc<8; kc++){
    int k0 = kc*32;
    {
      int row = t>>2, kk0 = (t&3)*8;
      const float4* src = (const float4*)(sln + (long)(l0+row)*256 + k0 + kk0);
      float4 v0 = src[0], v1 = src[1];
      a_s[kk0+0][row]=v0.x; a_s[kk0+1][row]=v0.y; a_s[kk0+2][row]=v0.z; a_s[kk0+3][row]=v0.w;
      a_s[kk0+4][row]=v1.x; a_s[kk0+5][row]=v1.y; a_s[kk0+6][row]=v1.z; a_s[kk0+7][row]=v1.w;
    }
    #pragma unroll
    for(int kk2=0; kk2<2; kk2++){
      int kk = (t>>4) + 16*kk2;
      *(float4*)&w_s[kk][(t&15)*4] = *(const float4*)(wpack + (long)(k0+kk)*PSTR + c0 + (t&15)*4);
    }
    __syncthreads();
    #pragma unroll 8
    for(int kk=0; kk<32; kk++){
      float4 a4 = *(const float4*)&a_s[kk][tr*4];
      float4 b4 = *(const float4*)&w_s[kk][tc*4];
      acc[0].x+=a4.x*b4.x; acc[0].y+=a4.x*b4.y; acc[0].z+=a4.x*b4.z; acc[0].w+=a4.x*b4.w;
      acc[1].x+=a4.y*b4.x; acc[1].y+=a4.y*b4.y; acc[1].z+=a4.y*b4.z; acc[1].w+=a4.y*b4.w;
      acc[2].x+=a4.z*b4.x; acc[2].y+=a4.z*b4.y; acc[2].z+=a4.z*b4.z; acc[2].w+=a4.z*b4.w;
      acc[3].x+=a4.w*b4.x; acc[3].y+=a4.w*b4.y; acc[3].z+=a4.w*b4.z; acc[3].w+=a4.w*b4.w;
    }
    __syncthreads();
  }
  #pragma unroll
  for(int r=0;r<4;r++)
    *(float4*)(proj + (long)(l0 + tr*4 + r)*PSTR + c0 + tc*4) = acc[r];
}

// ---------------- kernel 3: LayerNorm(z) stats + b_res = z_ln @ w_b
__global__ __launch_bounds__(256) void k_ln_z(const float* z, const float* sc, const float* bi,
                       const float* wb, float* murs, float* bres_t){
  int t = threadIdx.x;
  long rp0 = (long)blockIdx.x*32;
  int r = t>>3, part = t&7;
  long rp = rp0 + r;
  __shared__ __align__(16) float swb[8*132];   // [h][c] padded to 132
  __shared__ float SB[8][2];
  const float4* z4 = (const float4*)z;
  float4 x0 = z4[rp*32 + part*4 + 0];
  float4 x1 = z4[rp*32 + part*4 + 1];
  float4 x2 = z4[rp*32 + part*4 + 2];
  float4 x3 = z4[rp*32 + part*4 + 3];
  #pragma unroll
  for(int k2=0;k2<4;k2++){
    int e = t + k2*256; int h = e>>7, c = e&127;
    swb[h*132 + c] = sc[c]*wb[(long)c*8 + h];
  }
  __syncthreads();
  if(t < 64){
    int h = t>>3, seg = t&7;
    float S=0, Bv=0;
    #pragma unroll
    for(int i=0;i<16;i++){
      int c = seg*16+i;
      S  += swb[h*132+c];
      Bv += bi[c]*wb[(long)c*8 + h];
    }
    #pragma unroll
    for(int off=1;off<8;off<<=1){ S += __shfl_xor(S,off,64); Bv += __shfl_xor(Bv,off,64); }
    if(seg==0){ SB[h][0]=S; SB[h][1]=Bv; }
  }
  float s1 = x0.x+x0.y+x0.z+x0.w + x1.x+x1.y+x1.z+x1.w
           + x2.x+x2.y+x2.z+x2.w + x3.x+x3.y+x3.z+x3.w;
  float s2 = x0.x*x0.x+x0.y*x0.y+x0.z*x0.z+x0.w*x0.w
           + x1.x*x1.x+x1.y*x1.y+x1.z*x1.z+x1.w*x1.w
           + x2.x*x2.x+x2.y*x2.y+x2.z*x2.z+x2.w*x2.w
           + x3.x*x3.x+x3.y*x3.y+x3.z*x3.z+x3.w*x3.w;
  #pragma unroll
  for(int off=1;off<8;off<<=1){ s1 += __shfl_xor(s1,off,64); s2 += __shfl_xor(s2,off,64); }
  float mu = s1*(1.f/CZ);
  float var = s2*(1.f/CZ) - mu*mu;
  float rstd = rsqrtf(var + 1e-5f);
  if(part==0){ murs[rp*2]=mu; murs[rp*2+1]=rstd; }
  float acc[8];
  const float4* swb4 = (const float4*)swb;  // 33 float4 per h-row
  #pragma unroll
  for(int h=0;h<8;h++){
    float4 wa = swb4[h*33 + part*4 + 0];
    float4 wbv= swb4[h*33 + part*4 + 1];
    float4 wc = swb4[h*33 + part*4 + 2];
    float4 wd = swb4[h*33 + part*4 + 3];
    acc[h] = x0.x*wa.x + x0.y*wa.y + x0.z*wa.z + x0.w*wa.w
           + x1.x*wbv.x+ x1.y*wbv.y+ x1.z*wbv.z+ x1.w*wbv.w
           + x2.x*wc.x + x2.y*wc.y + x2.z*wc.z + x2.w*wc.w
           + x3.x*wd.x + x3.y*wd.y + x3.z*wd.z + x3.w*wd.w;
  }
  #pragma unroll
  for(int off=1;off<8;off<<=1){
    #pragma unroll
    for(int h=0;h<8;h++) acc[h] += __shfl_xor(acc[h],off,64);
  }
  __syncthreads();
  if(part==0){
    #pragma unroll
    for(int h=0;h<8;h++)
      bres_t[(long)h*147456 + rp] = rstd*(acc[h] - mu*SB[h][0]) + SB[h][1];
  }
}

// ---------------- kernel 4: rigid transforms + score-vector packing
__global__ __launch_bounds__(256) void k_rigid(const float* proj, const float* rot, const float* trans,
                        const float* mask, const float* hws,
                        float* qcat, float* kcat, float* vcat){
  int l = blockIdx.x, t = threadIdx.x;
  __shared__ float R[9], T[3], hwS[8], qgs[192], kgs[192];
  if(t<9) R[t]=rot[(long)l*9+t];
  if(t<3) T[t]=trans[(long)l*3+t];
  if(t>=16 && t<24) hwS[t-16] = log1pf(expf(hws[t-16]))*0.09622504486493764f;
  __syncthreads();
  const float* pr = proj + (long)l*PSTR;
  if(t<128){
    int h=t>>4, c=t&15;
    long base = ((long)h*L + l)*44;
    qcat[base + c] = 0.14433756729740643f * pr[t];
    kcat[base + c] = pr[128+t];
    vcat[((long)h*L + l)*64 + c] = pr[256+t];
  }
  if(t < 192){
    int h=t/24, m=t%24, p=m/3, i=m%3;
    float qa = R[i*3+0]*pr[384+h*24+p*3+0] + R[i*3+1]*pr[384+h*24+p*3+1]
             + R[i*3+2]*pr[384+h*24+p*3+2] + T[i];
    float ka = R[i*3+0]*pr[576+h*24+p*3+0] + R[i*3+1]*pr[576+h*24+p*3+1]
             + R[i*3+2]*pr[576+h*24+p*3+2] + T[i];
    qgs[t]=qa; kgs[t]=ka;
    long base = ((long)h*L + l)*44 + 16 + m;
    qcat[base] = hwS[h]*qa;
    kcat[base] = ka;
  }
  for(int it=t; it<288; it+=256){
    int h=it/36, m=it%36, p=m/3, i=m%3;
    float a = R[i*3+0]*pr[768+h*36+p*3+0] + R[i*3+1]*pr[768+h*36+p*3+1]
            + R[i*3+2]*pr[768+h*36+p*3+2] + T[i];
    vcat[((long)h*L + l)*64 + 16 + m] = a;
  }
  if(t < 96){
    int h=t/12, d=t%12;
    vcat[((long)h*L + l)*64 + 52 + d] = 0.f;
  }
  __syncthreads();
  if(t < 8){
    float qq=0, kk=0;
    #pragma unroll
    for(int m=0;m<24;m++){ qq += qgs[t*24+m]*qgs[t*24+m]; kk += kgs[t*24+m]*kgs[t*24+m]; }
    long base = ((long)t*L + l)*44;
    qcat[base + 40] = -0.5f*hwS[t]*qq;
    kcat[base + 40] = -0.5f*hwS[t]*kk + (mask[l]-1.f)*1e9f;
  }
}

// ---------------- kernel 5a: raw scores, 2D-tiled GEMM (K=40) ------
__global__ __launch_bounds__(256) void k_scores(const float* qcat, const float* kcat,
                         const float* bres_t, const int* ridx, float* attn){
  int l0 = blockIdx.x*32, j0 = blockIdx.y*64, h = blockIdx.z;
  int t = threadIdx.x;
  __shared__ __align__(16) float q_s[32*44];
  __shared__ __align__(16) float k_s[64*44];
  __shared__ int rj_s[64];
  {
    const float* srcq = qcat + ((long)h*L + l0)*44;
    for(int i=t; i<32*44; i+=256) q_s[i]=srcq[i];
    const float* srck = kcat + ((long)h*L + j0)*44;
    for(int i=t; i<64*44; i+=256) k_s[i]=srck[i];
    if(t<64) rj_s[t]=ridx[j0+t];
  }
  __syncthreads();
  int a = t>>5;   // row group 0..7
  int b = t&31;   // col group 0..31
  float acc[4][2] = {{0,0},{0,0},{0,0},{0,0}};
  const float4* q4 = (const float4*)q_s;
  const float4* k4 = (const float4*)k_s;
  #pragma unroll
  for(int i=0;i<10;i++){
    float4 kA = k4[(long)b*11 + i];
    float4 kB = k4[(long)(b+32)*11 + i];
    #pragma unroll
    for(int r=0;r<4;r++){
      float4 qv = q4[(long)(a+8*r)*11 + i];
      acc[r][0] += qv.x*kA.x + qv.y*kA.y + qv.z*kA.z + qv.w*kA.w;
      acc[r][1] += qv.x*kB.x + qv.y*kB.y + qv.z*kB.z + qv.w*kB.w;
    }
  }
  float colc0 = k_s[b*44+40], colc1 = k_s[(b+32)*44+40];
  int rj0 = rj_s[b], rj1 = rj_s[b+32];
  const float* bbh = bres_t + (long)h*147456;
  #pragma unroll
  for(int r=0;r<4;r++){
    int row = a+8*r;
    float rowc = q_s[row*44+40];
    int rl = ridx[l0+row];
    const float* bb = bbh + (long)rl*NRES;
    float s0 = acc[r][0] + rowc + colc0 + 0.5773502691896258f*bb[rj0];
    float s1 = acc[r][1] + rowc + colc1 + 0.5773502691896258f*bb[rj1];
    float* arow = attn + ((long)h*L + l0+row)*L + j0;
    arow[b]    = s0;
    arow[b+32] = s1;
  }
}

// ---------------- kernel 5b: row stats (max, 1/sum-exp) ------------
__global__ __launch_bounds__(256) void k_rowstat(const float* attn, float* rowstat){
  long row = (long)blockIdx.x*4 + (threadIdx.x>>6);
  int lane = threadIdx.x & 63;
  const float* p = attn + row*L;
  float v[18];
  float m=-1e30f;
  #pragma unroll
  for(int i=0;i<18;i++){ v[i]=p[lane + i*64]; m=fmaxf(m,v[i]); }
  #pragma unroll
  for(int off=1;off<64;off<<=1) m=fmaxf(m,__shfl_xor(m,off,64));
  float s=0;
  #pragma unroll
  for(int i=0;i<18;i++) s+=__expf(v[i]-m);
  #pragma unroll
  for(int off=1;off<64;off<<=1) s+=__shfl_xor(s,off,64);
  if(lane==0){ rowstat[row*2]=m; rowstat[row*2+1]=1.f/s; }
}

// ---------------- kernel 6a: split-K attn@vcat, softmax on the fly -
// grid (36, 8, 3); block: 32l x 64d, j-chunks sp*6..sp*6+5.
__global__ __launch_bounds__(256) void k_av(const float* attn, const float* vcat,
                     const float* rowstat, float* pav){
  int lb = blockIdx.x, h = blockIdx.y, sp = blockIdx.z, t = threadIdx.x;
  int l0 = lb*32;
  __shared__ float a_s[64][33];
  __shared__ __align__(16) float v_s[64][68];
  int lgrp = t>>4, dgrp = t&15;   // 16 x 16
  float4 acc0 = {0,0,0,0}, acc1 = {0,0,0,0};
  const float* abase = attn + ((long)h*L + l0)*L;
  int al = t>>3, jj0 = (t&7)*8;
  float mrow = rowstat[((long)h*L + l0 + al)*2];
  float irow = rowstat[((long)h*L + l0 + al)*2 + 1];
  for(int jc=sp*6; jc<sp*6+6; jc++){
    int j0 = jc*64;
    {
      const float4* src = (const float4*)(abase + (long)al*L + j0 + jj0);
      float4 p0 = src[0], p1 = src[1];
      a_s[jj0+0][al]=__expf(p0.x-mrow)*irow;
      a_s[jj0+1][al]=__expf(p0.y-mrow)*irow;
      a_s[jj0+2][al]=__expf(p0.z-mrow)*irow;
      a_s[jj0+3][al]=__expf(p0.w-mrow)*irow;
      a_s[jj0+4][al]=__expf(p1.x-mrow)*irow;
      a_s[jj0+5][al]=__expf(p1.y-mrow)*irow;
      a_s[jj0+6][al]=__expf(p1.z-mrow)*irow;
      a_s[jj0+7][al]=__expf(p1.w-mrow)*irow;
    }
    {
      int jj = t>>2, seg = t&3;
      const float4* src = (const float4*)(vcat + ((long)h*L + j0 + jj)*64 + seg*16);
      float4 q0=src[0], q1=src[1], q2=src[2], q3=src[3];
      float4* dst = (float4*)&v_s[jj][seg*16];
      dst[0]=q0; dst[1]=q1; dst[2]=q2; dst[3]=q3;
    }
    __syncthreads();
    #pragma unroll 8
    for(int jj=0; jj<64; jj++){
      float a0 = a_s[jj][lgrp*2], a1 = a_s[jj][lgrp*2+1];
      const float4 vv = *(const float4*)&v_s[jj][dgrp*4];
      acc0.x+=a0*vv.x; acc0.y+=a0*vv.y; acc0.z+=a0*vv.z; acc0.w+=a0*vv.w;
      acc1.x+=a1*vv.x; acc1.y+=a1*vv.y; acc1.z+=a1*vv.z; acc1.w+=a1*vv.w;
    }
    __syncthreads();
  }
  float* dst = pav + (((long)sp*H + h)*L + l0 + lgrp*2)*64 + dgrp*4;
  *(float4*)dst = acc0;
  *(float4*)(dst + 64) = acc1;
}

// ---------------- kernel 6b: reduce partials + epilogue ------------
__global__ __launch_bounds__(256) void k_avred(const float* pav, const float* rot, const float* trans,
                        float* cat){
  int lb = blockIdx.x, h = blockIdx.y, t = threadIdx.x;
  int l0 = lb*32;
  __shared__ __align__(16) float fin_s[32][64];
  #pragma unroll
  for(int k=0;k<2;k++){
    int fi = t + k*256;             // float4 idx 0..511
    int l = fi>>4, c4 = fi&15;
    long base = (((long)h)*L + l0 + l)*64 + c4*4;
    float4 a = *(const float4*)(pav + base);
    float4 b = *(const float4*)(pav + 589824 + base);
    float4 c = *(const float4*)(pav + 1179648 + base);
    float4 r = {a.x+b.x+c.x, a.y+b.y+c.y, a.z+b.z+c.z, a.w+b.w+c.w};
    *(float4*)&fin_s[l][c4*4] = r;
  }
  __syncthreads();
  for(int it=t; it<32*16; it+=256){
    int l=it>>4, c=it&15;
    cat[(long)(l0+l)*1536 + h*192 + c] = fin_s[l][c];
  }
  for(int it=t; it<32*12; it+=256){
    int l=it/12, p=it%12;
    long gl = l0+l;
    float og0 = fin_s[l][16+p*3+0]-trans[gl*3+0];
    float og1 = fin_s[l][16+p*3+1]-trans[gl*3+1];
    float og2 = fin_s[l][16+p*3+2]-trans[gl*3+2];
    float* crow = cat + gl*1536 + h*192;
    float nrm=0;
    #pragma unroll
    for(int i=0;i<3;i++){
      float v = rot[gl*9+0+i]*og0 + rot[gl*9+3+i]*og1 + rot[gl*9+6+i]*og2;
      crow[16+p*3+i]=v; nrm+=v*v;
    }
    crow[52+p]=sqrtf(nrm+1e-8f);
  }
}

// ---------------- kernel 7: o_pair, trio-fused, softmax on the fly -
__global__ __launch_bounds__(256) void k_opair(const float* attn, const float* z, const float* murs,
                        const float* rowstat,
                        const float* sc, const float* bi, const int* ridx, float* cat){
  int r=blockIdx.x, t=threadIdx.x;
  __shared__ __align__(16) float ar[3][H][NRES];   // 36 KB
  __shared__ __align__(16) float mrs[NRES*2];
  __shared__ float rs_s[24][2];
  int rl = ridx[r*3];
  if(t<24){
    int lo=t/8, h=t%8;
    long row = (long)h*L + r*3+lo;
    rs_s[t][0]=rowstat[row*2]; rs_s[t][1]=rowstat[row*2+1];
  }
  __syncthreads();
  for(int it=t; it<3*H*NRES; it+=256){
    int lo = it/(H*NRES);
    int rem = it - lo*(H*NRES);
    int h = rem/NRES, n = rem - h*NRES;
    const float* arow = attn + ((long)h*L + r*3+lo)*L + n*3;
    float m = rs_s[lo*8+h][0], iv = rs_s[lo*8+h][1];
    ar[lo][h][n]=(__expf(arow[0]-m)+__expf(arow[1]-m)+__expf(arow[2]-m))*iv;
  }
  for(int i=t;i<NRES*2;i+=256) mrs[i]=murs[(long)rl*NRES*2 + i];
  __syncthreads();
  int tc=t&63, th=t>>6;
  int c0=tc*2, h0=th*2;
  float sc0=sc[c0], sc1=sc[c0+1], bi0=bi[c0], bi1=bi[c0+1];
  float acc[3][2][2]={};
  const float* zbase = z + ((long)rl*NRES)*CZ + c0;
  for(int n=0;n<NRES;n+=2){
    float4 mr4 = *(const float4*)&mrs[n*2];   // mu0,rs0,mu1,rs1
    float2 z0 = *(const float2*)(zbase + (long)n*CZ);
    float2 z1 = *(const float2*)(zbase + (long)(n+1)*CZ);
    float zv00 = (z0.x - mr4.x)*mr4.y*sc0 + bi0;
    float zv01 = (z0.y - mr4.x)*mr4.y*sc1 + bi1;
    float zv10 = (z1.x - mr4.z)*mr4.w*sc0 + bi0;
    float zv11 = (z1.y - mr4.z)*mr4.w*sc1 + bi1;
    #pragma unroll
    for(int lo=0;lo<3;lo++){
      #pragma unroll
      for(int hp=0;hp<2;hp++){
        float2 a2 = *(const float2*)&ar[lo][h0+hp][n];
        acc[lo][hp][0] += a2.x*zv00 + a2.y*zv10;
        acc[lo][hp][1] += a2.x*zv01 + a2.y*zv11;
      }
    }
  }
  #pragma unroll
  for(int lo=0;lo<3;lo++){
    float* crow = cat + (long)(r*3+lo)*1536;
    #pragma unroll
    for(int hp=0;hp<2;hp++){
      crow[(h0+hp)*192+64+c0]   = acc[lo][hp][0];
      crow[(h0+hp)*192+64+c0+1] = acc[lo][hp][1];
    }
  }
}

// ---------------- kernel 8a: final GEMM, split-K x4 ----------------
__global__ __launch_bounds__(256) void k_final(const float* cat, const float* wout, float* pcat){
  int l0 = blockIdx.x*32, c0 = blockIdx.y*32, kp = blockIdx.z, t = threadIdx.x;
  __shared__ float a_s[64][33];
  __shared__ __align__(16) float w_s[64][36];
  int tr = t>>3, tc = t&7;
  float4 acc = {0,0,0,0};
  for(int kc=0; kc<6; kc++){
    int k0 = kp*384 + kc*64;
    {
      int row = t>>3, kk0 = (t&7)*8;
      const float4* src = (const float4*)(cat + (long)(l0+row)*1536 + k0 + kk0);
      float4 v0 = src[0], v1 = src[1];
      a_s[kk0+0][row]=v0.x; a_s[kk0+1][row]=v0.y; a_s[kk0+2][row]=v0.z; a_s[kk0+3][row]=v0.w;
      a_s[kk0+4][row]=v1.x; a_s[kk0+5][row]=v1.y; a_s[kk0+6][row]=v1.z; a_s[kk0+7][row]=v1.w;
    }
    #pragma unroll
    for(int kk2=0; kk2<2; kk2++){
      int kk = (t>>3) + 32*kk2;
      *(float4*)&w_s[kk][(t&7)*4] = *(const float4*)(wout + (long)(k0+kk)*256 + c0 + (t&7)*4);
    }
    __syncthreads();
    #pragma unroll 8
    for(int kk=0; kk<64; kk++){
      float a0 = a_s[kk][tr];
      float4 b4 = *(const float4*)&w_s[kk][tc*4];
      acc.x+=a0*b4.x; acc.y+=a0*b4.y; acc.z+=a0*b4.z; acc.w+=a0*b4.w;
    }
    __syncthreads();
  }
  *(float4*)(pcat + ((long)kp*L + l0+tr)*256 + c0 + tc*4) = acc;
}

// ---------------- kernel 8b: reduce partials + bias ----------------
__global__ __launch_bounds__(256) void k_redout(const float* pcat, const float* bout, float* out){
  int i = blockIdx.x*256 + threadIdx.x;    // float4 index over 73728
  const float4* p = (const float4*)pcat;
  float4 a = p[i], b = p[i+73728], c = p[i+147456], d = p[i+221184];
  float4 bv = ((const float4*)bout)[i&63];
  float4 r;
  r.x = a.x+b.x+c.x+d.x+bv.x;
  r.y = a.y+b.y+c.y+d.y+bv.y;
  r.z = a.z+b.z+c.z+d.z+bv.z;
  r.w = a.w+b.w+c.w+d.w+bv.w;
  ((float4*)out)[i] = r;
}

extern "C" void kernel_launch(void* const* d_in, const int* in_sizes, int n_in,
                              void* d_out, int out_size, void* d_ws, size_t ws_size,
                              hipStream_t stream) {
  const float* s      = (const float*)d_in[0];
  const float* z      = (const float*)d_in[1];
  const float* rot    = (const float*)d_in[2];
  const float* trans  = (const float*)d_in[3];
  const float* mask   = (const float*)d_in[4];
  const float* lnss   = (const float*)d_in[5];
  const float* lnsb   = (const float*)d_in[6];
  const float* lnzs   = (const float*)d_in[7];
  const float* lnzb   = (const float*)d_in[8];
  const float* wq     = (const float*)d_in[9];
  const float* wk     = (const float*)d_in[10];
  const float* wv     = (const float*)d_in[11];
  const float* wqp    = (const float*)d_in[12];
  const float* wkp    = (const float*)d_in[13];
  const float* wvp    = (const float*)d_in[14];
  const float* wb     = (const float*)d_in[15];
  const float* hws    = (const float*)d_in[16];
  const float* wout   = (const float*)d_in[17];
  const float* bout   = (const float*)d_in[18];
  const int*  ridx    = (const int*)d_in[19];

  float* ws  = (float*)d_ws;
  float* out = (float*)d_out;

  float* sln  = ws + OFF_SLN;
  float* proj = ws + OFF_PROJ;
  float* wpk  = ws + OFF_WPK;
  float* qcat = ws + OFF_QCAT;
  float* kcat = ws + OFF_KCAT;
  float* vcat = ws + OFF_VCAT;
  float* bres = ws + OFF_BRES;
  float* murs = ws + OFF_MURS;
  float* attn = ws + OFF_ATTN;
  float* cat  = ws + OFF_CAT;
  float* pcat = ws + OFF_PCAT;
  float* rstat= ws + OFF_RSTAT;
  float* pav  = ws + OFF_PAV;    // aliases sln/proj/wpk (dead by then)

  k_packw<<<dim3(256), dim3(256), 0, stream>>>(wq, wk, wv, wqp, wkp, wvp, wpk);
  k_ln_s<<<dim3(L), dim3(CS), 0, stream>>>(s, lnss, lnsb, sln);
  k_proj<<<dim3(18,17), dim3(256), 0, stream>>>(sln, wpk, proj);
  k_ln_z<<<dim3(NRES*NRES/32), dim3(256), 0, stream>>>(z, lnzs, lnzb, wb, murs, bres);
  k_rigid<<<dim3(L), dim3(256), 0, stream>>>(proj, rot, trans, mask, hws, qcat, kcat, vcat);
  k_scores<<<dim3(L/32, L/64, H), dim3(256), 0, stream>>>(qcat, kcat, bres, ridx, attn);
  k_rowstat<<<dim3(H*L/4), dim3(256), 0, stream>>>(attn, rstat);
  k_av<<<dim3(L/32, H, 3), dim3(256), 0, stream>>>(attn, vcat, rstat, pav);
  k_avred<<<dim3(L/32, H), dim3(256), 0, stream>>>(pav, rot, trans, cat);
  k_opair<<<dim3(NRES), dim3(256), 0, stream>>>(attn, z, murs, rstat, lnzs, lnzb, ridx, cat);
  k_final<<<dim3(36,8,4), dim3(256), 0, stream>>>(cat, wout, pcat);
  k_redout<<<dim3(288), dim3(256), 0, stream>>>(pcat, bout, out);
}

// Round 11
// 338.623 us; speedup vs baseline: 5.4900x; 1.0006x over previous
//
#include <hip/hip_runtime.h>
#include <hip/hip_bf16.h>

#define L 1152
#define NRES 384
#define CS 256
#define CZ 128
#define H 8
#define CH 16
#define PQ 8
#define PV 12
#define PSTR 1088   // padded projection row stride (17*64)

// workspace offsets (in floats)
#define OFF_SLN  0L          // 1152*256      = 294912
#define OFF_PROJ 294912L     // 1152*1088     = 1253376
#define OFF_WPK  1548288L    // 256*1088      = 278528
#define OFF_QCAT 1826816L    // 8*1152*44     = 405504
#define OFF_KCAT 2232320L    // 8*1152*44     = 405504
#define OFF_VCAT 2637824L    // 8*1152*64     = 589824
#define OFF_BRES 3227648L    // 8*147456      = 1179648 (transposed [h][rp])
#define OFF_MURS 4407296L    // 384*384*2     = 294912
#define OFF_ATTN 4702208L    // 8*1152*1152   = 10616832
#define OFF_CAT  15319040L   // 1152*1536     = 1769472
#define OFF_PCAT 17088512L   // 4*1152*256    = 1179648
#define OFF_RSTAT 18268160L  // 9216*2        = 18432
// pav (3*8*1152*64 = 1769472) aliases OFF_SLN.. (dead after k_rigid)
#define OFF_PAV  0L
// po (2*1152*1024 = 2359296) aliases OFF_SLN..2359296 (pav dead after k_avred)
#define OFF_POP  0L
// total fp32: 18286592 floats = 73.1 MB

// ---------------- kernel 1: LayerNorm(s) -> fp32 -------------------
__global__ __launch_bounds__(256) void k_ln_s(const float* s, const float* sc, const float* bi, float* sln){
  int l = blockIdx.x, t = threadIdx.x;
  __shared__ float red[CS];
  float x = s[(long)l*CS + t];
  red[t] = x; __syncthreads();
  for(int st=128; st>0; st>>=1){ if(t<st) red[t]+=red[t+st]; __syncthreads(); }
  float mu = red[0] * (1.f/CS); __syncthreads();
  float d = x - mu;
  red[t] = d*d; __syncthreads();
  for(int st=128; st>0; st>>=1){ if(t<st) red[t]+=red[t+st]; __syncthreads(); }
  float var = red[0]*(1.f/CS);
  sln[(long)l*CS + t] = d*rsqrtf(var + 1e-5f)*sc[t] + bi[t];
}

// ---------------- kernel 1b: pack six weight mats into wpack[256][1088]
__global__ __launch_bounds__(256) void k_packw(const float* wq, const float* wk, const float* wv,
                        const float* wqp, const float* wkp, const float* wvp, float* wpack){
  int k = blockIdx.x, t = threadIdx.x;
  for(int c=t; c<PSTR; c+=256){
    float v;
    if(c<128)        v = wq [(long)k*128 + c];
    else if(c<256)   v = wk [(long)k*128 + c-128];
    else if(c<384)   v = wv [(long)k*128 + c-256];
    else if(c<576)   v = wqp[(long)k*192 + c-384];
    else if(c<768)   v = wkp[(long)k*192 + c-576];
    else if(c<1056)  v = wvp[(long)k*288 + c-768];
    else             v = 0.f;
    wpack[(long)k*PSTR + c] = v;
  }
}

// ---------------- kernel 2: projections as tiled GEMM --------------
__global__ __launch_bounds__(256) void k_proj(const float* sln, const float* wpack, float* proj){
  int l0 = blockIdx.x*64, c0 = blockIdx.y*64, t = threadIdx.x;
  __shared__ float a_s[32][68];
  __shared__ __align__(16) float w_s[32][68];
  int tr = t>>4, tc = t&15;
  float4 acc[4] = {{0,0,0,0},{0,0,0,0},{0,0,0,0},{0,0,0,0}};
  for(int kc=0; kc<8; kc++){
    int k0 = kc*32;
    {
      int row = t>>2, kk0 = (t&3)*8;
      const float4* src = (const float4*)(sln + (long)(l0+row)*256 + k0 + kk0);
      float4 v0 = src[0], v1 = src[1];
      a_s[kk0+0][row]=v0.x; a_s[kk0+1][row]=v0.y; a_s[kk0+2][row]=v0.z; a_s[kk0+3][row]=v0.w;
      a_s[kk0+4][row]=v1.x; a_s[kk0+5][row]=v1.y; a_s[kk0+6][row]=v1.z; a_s[kk0+7][row]=v1.w;
    }
    #pragma unroll
    for(int kk2=0; kk2<2; kk2++){
      int kk = (t>>4) + 16*kk2;
      *(float4*)&w_s[kk][(t&15)*4] = *(const float4*)(wpack + (long)(k0+kk)*PSTR + c0 + (t&15)*4);
    }
    __syncthreads();
    #pragma unroll 8
    for(int kk=0; kk<32; kk++){
      float4 a4 = *(const float4*)&a_s[kk][tr*4];
      float4 b4 = *(const float4*)&w_s[kk][tc*4];
      acc[0].x+=a4.x*b4.x; acc[0].y+=a4.x*b4.y; acc[0].z+=a4.x*b4.z; acc[0].w+=a4.x*b4.w;
      acc[1].x+=a4.y*b4.x; acc[1].y+=a4.y*b4.y; acc[1].z+=a4.y*b4.z; acc[1].w+=a4.y*b4.w;
      acc[2].x+=a4.z*b4.x; acc[2].y+=a4.z*b4.y; acc[2].z+=a4.z*b4.z; acc[2].w+=a4.z*b4.w;
      acc[3].x+=a4.w*b4.x; acc[3].y+=a4.w*b4.y; acc[3].z+=a4.w*b4.z; acc[3].w+=a4.w*b4.w;
    }
    __syncthreads();
  }
  #pragma unroll
  for(int r=0;r<4;r++)
    *(float4*)(proj + (long)(l0 + tr*4 + r)*PSTR + c0 + tc*4) = acc[r];
}

// ---------------- kernel 3: LayerNorm(z) stats + b_res = z_ln @ w_b
__global__ __launch_bounds__(256) void k_ln_z(const float* z, const float* sc, const float* bi,
                       const float* wb, float* murs, float* bres_t){
  int t = threadIdx.x;
  long rp0 = (long)blockIdx.x*32;
  int r = t>>3, part = t&7;
  long rp = rp0 + r;
  __shared__ __align__(16) float swb[8*132];   // [h][c] padded to 132
  __shared__ float SB[8][2];
  const float4* z4 = (const float4*)z;
  float4 x0 = z4[rp*32 + part*4 + 0];
  float4 x1 = z4[rp*32 + part*4 + 1];
  float4 x2 = z4[rp*32 + part*4 + 2];
  float4 x3 = z4[rp*32 + part*4 + 3];
  #pragma unroll
  for(int k2=0;k2<4;k2++){
    int e = t + k2*256; int h = e>>7, c = e&127;
    swb[h*132 + c] = sc[c]*wb[(long)c*8 + h];
  }
  __syncthreads();
  if(t < 64){
    int h = t>>3, seg = t&7;
    float S=0, Bv=0;
    #pragma unroll
    for(int i=0;i<16;i++){
      int c = seg*16+i;
      S  += swb[h*132+c];
      Bv += bi[c]*wb[(long)c*8 + h];
    }
    #pragma unroll
    for(int off=1;off<8;off<<=1){ S += __shfl_xor(S,off,64); Bv += __shfl_xor(Bv,off,64); }
    if(seg==0){ SB[h][0]=S; SB[h][1]=Bv; }
  }
  float s1 = x0.x+x0.y+x0.z+x0.w + x1.x+x1.y+x1.z+x1.w
           + x2.x+x2.y+x2.z+x2.w + x3.x+x3.y+x3.z+x3.w;
  float s2 = x0.x*x0.x+x0.y*x0.y+x0.z*x0.z+x0.w*x0.w
           + x1.x*x1.x+x1.y*x1.y+x1.z*x1.z+x1.w*x1.w
           + x2.x*x2.x+x2.y*x2.y+x2.z*x2.z+x2.w*x2.w
           + x3.x*x3.x+x3.y*x3.y+x3.z*x3.z+x3.w*x3.w;
  #pragma unroll
  for(int off=1;off<8;off<<=1){ s1 += __shfl_xor(s1,off,64); s2 += __shfl_xor(s2,off,64); }
  float mu = s1*(1.f/CZ);
  float var = s2*(1.f/CZ) - mu*mu;
  float rstd = rsqrtf(var + 1e-5f);
  if(part==0){ murs[rp*2]=mu; murs[rp*2+1]=rstd; }
  float acc[8];
  const float4* swb4 = (const float4*)swb;  // 33 float4 per h-row
  #pragma unroll
  for(int h=0;h<8;h++){
    float4 wa = swb4[h*33 + part*4 + 0];
    float4 wbv= swb4[h*33 + part*4 + 1];
    float4 wc = swb4[h*33 + part*4 + 2];
    float4 wd = swb4[h*33 + part*4 + 3];
    acc[h] = x0.x*wa.x + x0.y*wa.y + x0.z*wa.z + x0.w*wa.w
           + x1.x*wbv.x+ x1.y*wbv.y+ x1.z*wbv.z+ x1.w*wbv.w
           + x2.x*wc.x + x2.y*wc.y + x2.z*wc.z + x2.w*wc.w
           + x3.x*wd.x + x3.y*wd.y + x3.z*wd.z + x3.w*wd.w;
  }
  #pragma unroll
  for(int off=1;off<8;off<<=1){
    #pragma unroll
    for(int h=0;h<8;h++) acc[h] += __shfl_xor(acc[h],off,64);
  }
  __syncthreads();
  if(part==0){
    #pragma unroll
    for(int h=0;h<8;h++)
      bres_t[(long)h*147456 + rp] = rstd*(acc[h] - mu*SB[h][0]) + SB[h][1];
  }
}

// ---------------- kernel 4: rigid transforms + score-vector packing
__global__ __launch_bounds__(256) void k_rigid(const float* proj, const float* rot, const float* trans,
                        const float* mask, const float* hws,
                        float* qcat, float* kcat, float* vcat){
  int l = blockIdx.x, t = threadIdx.x;
  __shared__ float R[9], T[3], hwS[8], qgs[192], kgs[192];
  if(t<9) R[t]=rot[(long)l*9+t];
  if(t<3) T[t]=trans[(long)l*3+t];
  if(t>=16 && t<24) hwS[t-16] = log1pf(expf(hws[t-16]))*0.09622504486493764f;
  __syncthreads();
  const float* pr = proj + (long)l*PSTR;
  if(t<128){
    int h=t>>4, c=t&15;
    long base = ((long)h*L + l)*44;
    qcat[base + c] = 0.14433756729740643f * pr[t];
    kcat[base + c] = pr[128+t];
    vcat[((long)h*L + l)*64 + c] = pr[256+t];
  }
  if(t < 192){
    int h=t/24, m=t%24, p=m/3, i=m%3;
    float qa = R[i*3+0]*pr[384+h*24+p*3+0] + R[i*3+1]*pr[384+h*24+p*3+1]
             + R[i*3+2]*pr[384+h*24+p*3+2] + T[i];
    float ka = R[i*3+0]*pr[576+h*24+p*3+0] + R[i*3+1]*pr[576+h*24+p*3+1]
             + R[i*3+2]*pr[576+h*24+p*3+2] + T[i];
    qgs[t]=qa; kgs[t]=ka;
    long base = ((long)h*L + l)*44 + 16 + m;
    qcat[base] = hwS[h]*qa;
    kcat[base] = ka;
  }
  for(int it=t; it<288; it+=256){
    int h=it/36, m=it%36, p=m/3, i=m%3;
    float a = R[i*3+0]*pr[768+h*36+p*3+0] + R[i*3+1]*pr[768+h*36+p*3+1]
            + R[i*3+2]*pr[768+h*36+p*3+2] + T[i];
    vcat[((long)h*L + l)*64 + 16 + m] = a;
  }
  if(t < 96){
    int h=t/12, d=t%12;
    vcat[((long)h*L + l)*64 + 52 + d] = 0.f;
  }
  __syncthreads();
  if(t < 8){
    float qq=0, kk=0;
    #pragma unroll
    for(int m=0;m<24;m++){ qq += qgs[t*24+m]*qgs[t*24+m]; kk += kgs[t*24+m]*kgs[t*24+m]; }
    long base = ((long)t*L + l)*44;
    qcat[base + 40] = -0.5f*hwS[t]*qq;
    kcat[base + 40] = -0.5f*hwS[t]*kk + (mask[l]-1.f)*1e9f;
  }
}

// ---------------- kernel 5a: raw scores, 2D-tiled GEMM (K=40) ------
__global__ __launch_bounds__(256) void k_scores(const float* qcat, const float* kcat,
                         const float* bres_t, const int* ridx, float* attn){
  int l0 = blockIdx.x*32, j0 = blockIdx.y*64, h = blockIdx.z;
  int t = threadIdx.x;
  __shared__ __align__(16) float q_s[32*44];
  __shared__ __align__(16) float k_s[64*44];
  __shared__ int rj_s[64];
  {
    const float* srcq = qcat + ((long)h*L + l0)*44;
    for(int i=t; i<32*44; i+=256) q_s[i]=srcq[i];
    const float* srck = kcat + ((long)h*L + j0)*44;
    for(int i=t; i<64*44; i+=256) k_s[i]=srck[i];
    if(t<64) rj_s[t]=ridx[j0+t];
  }
  __syncthreads();
  int a = t>>5;   // row group 0..7
  int b = t&31;   // col group 0..31
  float acc[4][2] = {{0,0},{0,0},{0,0},{0,0}};
  const float4* q4 = (const float4*)q_s;
  const float4* k4 = (const float4*)k_s;
  #pragma unroll
  for(int i=0;i<10;i++){
    float4 kA = k4[(long)b*11 + i];
    float4 kB = k4[(long)(b+32)*11 + i];
    #pragma unroll
    for(int r=0;r<4;r++){
      float4 qv = q4[(long)(a+8*r)*11 + i];
      acc[r][0] += qv.x*kA.x + qv.y*kA.y + qv.z*kA.z + qv.w*kA.w;
      acc[r][1] += qv.x*kB.x + qv.y*kB.y + qv.z*kB.z + qv.w*kB.w;
    }
  }
  float colc0 = k_s[b*44+40], colc1 = k_s[(b+32)*44+40];
  int rj0 = rj_s[b], rj1 = rj_s[b+32];
  const float* bbh = bres_t + (long)h*147456;
  #pragma unroll
  for(int r=0;r<4;r++){
    int row = a+8*r;
    float rowc = q_s[row*44+40];
    int rl = ridx[l0+row];
    const float* bb = bbh + (long)rl*NRES;
    float s0 = acc[r][0] + rowc + colc0 + 0.5773502691896258f*bb[rj0];
    float s1 = acc[r][1] + rowc + colc1 + 0.5773502691896258f*bb[rj1];
    float* arow = attn + ((long)h*L + l0+row)*L + j0;
    arow[b]    = s0;
    arow[b+32] = s1;
  }
}

// ---------------- kernel 5b: row stats (max, 1/sum-exp) ------------
__global__ __launch_bounds__(256) void k_rowstat(const float* attn, float* rowstat){
  long row = (long)blockIdx.x*4 + (threadIdx.x>>6);
  int lane = threadIdx.x & 63;
  const float* p = attn + row*L;
  float v[18];
  float m=-1e30f;
  #pragma unroll
  for(int i=0;i<18;i++){ v[i]=p[lane + i*64]; m=fmaxf(m,v[i]); }
  #pragma unroll
  for(int off=1;off<64;off<<=1) m=fmaxf(m,__shfl_xor(m,off,64));
  float s=0;
  #pragma unroll
  for(int i=0;i<18;i++) s+=__expf(v[i]-m);
  #pragma unroll
  for(int off=1;off<64;off<<=1) s+=__shfl_xor(s,off,64);
  if(lane==0){ rowstat[row*2]=m; rowstat[row*2+1]=1.f/s; }
}

// ---------------- kernel 6a: split-K attn@vcat, softmax on the fly -
__global__ __launch_bounds__(256) void k_av(const float* attn, const float* vcat,
                     const float* rowstat, float* pav){
  int lb = blockIdx.x, h = blockIdx.y, sp = blockIdx.z, t = threadIdx.x;
  int l0 = lb*32;
  __shared__ float a_s[64][33];
  __shared__ __align__(16) float v_s[64][68];
  int lgrp = t>>4, dgrp = t&15;   // 16 x 16
  float4 acc0 = {0,0,0,0}, acc1 = {0,0,0,0};
  const float* abase = attn + ((long)h*L + l0)*L;
  int al = t>>3, jj0 = (t&7)*8;
  float mrow = rowstat[((long)h*L + l0 + al)*2];
  float irow = rowstat[((long)h*L + l0 + al)*2 + 1];
  for(int jc=sp*6; jc<sp*6+6; jc++){
    int j0 = jc*64;
    {
      const float4* src = (const float4*)(abase + (long)al*L + j0 + jj0);
      float4 p0 = src[0], p1 = src[1];
      a_s[jj0+0][al]=__expf(p0.x-mrow)*irow;
      a_s[jj0+1][al]=__expf(p0.y-mrow)*irow;
      a_s[jj0+2][al]=__expf(p0.z-mrow)*irow;
      a_s[jj0+3][al]=__expf(p0.w-mrow)*irow;
      a_s[jj0+4][al]=__expf(p1.x-mrow)*irow;
      a_s[jj0+5][al]=__expf(p1.y-mrow)*irow;
      a_s[jj0+6][al]=__expf(p1.z-mrow)*irow;
      a_s[jj0+7][al]=__expf(p1.w-mrow)*irow;
    }
    {
      int jj = t>>2, seg = t&3;
      const float4* src = (const float4*)(vcat + ((long)h*L + j0 + jj)*64 + seg*16);
      float4 q0=src[0], q1=src[1], q2=src[2], q3=src[3];
      float4* dst = (float4*)&v_s[jj][seg*16];
      dst[0]=q0; dst[1]=q1; dst[2]=q2; dst[3]=q3;
    }
    __syncthreads();
    #pragma unroll 8
    for(int jj=0; jj<64; jj++){
      float a0 = a_s[jj][lgrp*2], a1 = a_s[jj][lgrp*2+1];
      const float4 vv = *(const float4*)&v_s[jj][dgrp*4];
      acc0.x+=a0*vv.x; acc0.y+=a0*vv.y; acc0.z+=a0*vv.z; acc0.w+=a0*vv.w;
      acc1.x+=a1*vv.x; acc1.y+=a1*vv.y; acc1.z+=a1*vv.z; acc1.w+=a1*vv.w;
    }
    __syncthreads();
  }
  float* dst = pav + (((long)sp*H + h)*L + l0 + lgrp*2)*64 + dgrp*4;
  *(float4*)dst = acc0;
  *(float4*)(dst + 64) = acc1;
}

// ---------------- kernel 6b: reduce partials + epilogue ------------
__global__ __launch_bounds__(256) void k_avred(const float* pav, const float* rot, const float* trans,
                        float* cat){
  int lb = blockIdx.x, h = blockIdx.y, t = threadIdx.x;
  int l0 = lb*32;
  __shared__ __align__(16) float fin_s[32][64];
  #pragma unroll
  for(int k=0;k<2;k++){
    int fi = t + k*256;             // float4 idx 0..511
    int l = fi>>4, c4 = fi&15;
    long base = (((long)h)*L + l0 + l)*64 + c4*4;
    float4 a = *(const float4*)(pav + base);
    float4 b = *(const float4*)(pav + 589824 + base);
    float4 c = *(const float4*)(pav + 1179648 + base);
    float4 r = {a.x+b.x+c.x, a.y+b.y+c.y, a.z+b.z+c.z, a.w+b.w+c.w};
    *(float4*)&fin_s[l][c4*4] = r;
  }
  __syncthreads();
  for(int it=t; it<32*16; it+=256){
    int l=it>>4, c=it&15;
    cat[(long)(l0+l)*1536 + h*192 + c] = fin_s[l][c];
  }
  for(int it=t; it<32*12; it+=256){
    int l=it/12, p=it%12;
    long gl = l0+l;
    float og0 = fin_s[l][16+p*3+0]-trans[gl*3+0];
    float og1 = fin_s[l][16+p*3+1]-trans[gl*3+1];
    float og2 = fin_s[l][16+p*3+2]-trans[gl*3+2];
    float* crow = cat + gl*1536 + h*192;
    float nrm=0;
    #pragma unroll
    for(int i=0;i<3;i++){
      float v = rot[gl*9+0+i]*og0 + rot[gl*9+3+i]*og1 + rot[gl*9+6+i]*og2;
      crow[16+p*3+i]=v; nrm+=v*v;
    }
    crow[52+p]=sqrtf(nrm+1e-8f);
  }
}

// ---------------- kernel 7a: o_pair, trio-fused + split-N x2 -------
// grid (384, 2): residue r, n-range [sp*192, sp*192+192)
__global__ __launch_bounds__(256) void k_opair(const float* attn, const float* z, const float* murs,
                        const float* rowstat,
                        const float* sc, const float* bi, const int* ridx, float* po){
  int r=blockIdx.x, sp=blockIdx.y, t=threadIdx.x;
  __shared__ __align__(16) float ar[3][H][192];   // 18 KB
  __shared__ __align__(16) float mrs[192*2];
  __shared__ float rs_s[24][2];
  int rl = ridx[r*3];
  int n0 = sp*192;
  if(t<24){
    int lo=t/8, h=t%8;
    long row = (long)h*L + r*3+lo;
    rs_s[t][0]=rowstat[row*2]; rs_s[t][1]=rowstat[row*2+1];
  }
  __syncthreads();
  for(int it=t; it<3*H*192; it+=256){
    int lo = it/(H*192);
    int rem = it - lo*(H*192);
    int h = rem/192, n = rem - h*192;
    const float* arow = attn + ((long)h*L + r*3+lo)*L + (n0+n)*3;
    float m = rs_s[lo*8+h][0], iv = rs_s[lo*8+h][1];
    ar[lo][h][n]=(__expf(arow[0]-m)+__expf(arow[1]-m)+__expf(arow[2]-m))*iv;
  }
  for(int i=t;i<192*2;i+=256) mrs[i]=murs[((long)rl*NRES + n0)*2 + i];
  __syncthreads();
  int tc=t&63, th=t>>6;
  int c0=tc*2, h0=th*2;
  float sc0=sc[c0], sc1=sc[c0+1], bi0=bi[c0], bi1=bi[c0+1];
  float acc[3][2][2]={};
  const float* zbase = z + ((long)(rl*NRES + n0))*CZ + c0;
  for(int n=0;n<192;n+=2){
    float4 mr4 = *(const float4*)&mrs[n*2];   // mu0,rs0,mu1,rs1
    float2 z0 = *(const float2*)(zbase + (long)n*CZ);
    float2 z1 = *(const float2*)(zbase + (long)(n+1)*CZ);
    float zv00 = (z0.x - mr4.x)*mr4.y*sc0 + bi0;
    float zv01 = (z0.y - mr4.x)*mr4.y*sc1 + bi1;
    float zv10 = (z1.x - mr4.z)*mr4.w*sc0 + bi0;
    float zv11 = (z1.y - mr4.z)*mr4.w*sc1 + bi1;
    #pragma unroll
    for(int lo=0;lo<3;lo++){
      #pragma unroll
      for(int hp=0;hp<2;hp++){
        float2 a2 = *(const float2*)&ar[lo][h0+hp][n];
        acc[lo][hp][0] += a2.x*zv00 + a2.y*zv10;
        acc[lo][hp][1] += a2.x*zv01 + a2.y*zv11;
      }
    }
  }
  #pragma unroll
  for(int lo=0;lo<3;lo++){
    float* prow = po + ((long)sp*L + r*3+lo)*1024;
    #pragma unroll
    for(int hp=0;hp<2;hp++){
      float2 w = {acc[lo][hp][0], acc[lo][hp][1]};
      *(float2*)&prow[(h0+hp)*128 + c0] = w;
    }
  }
}

// ---------------- kernel 7b: reduce o_pair partials into cat -------
__global__ __launch_bounds__(256) void k_opred(const float* po, float* cat){
  int i = blockIdx.x*256 + threadIdx.x;    // float4 idx over 294912
  const float4* p = (const float4*)po;
  float4 a = p[i], b = p[i + 294912];
  int l = i>>8, rem = i&255;
  int h = rem>>5, c4 = rem&31;
  float4 r = {a.x+b.x, a.y+b.y, a.z+b.z, a.w+b.w};
  ((float4*)cat)[(long)l*384 + h*48 + 16 + c4] = r;
}

// ---------------- kernel 8a: final GEMM, split-K x4 ----------------
__global__ __launch_bounds__(256) void k_final(const float* cat, const float* wout, float* pcat){
  int l0 = blockIdx.x*32, c0 = blockIdx.y*32, kp = blockIdx.z, t = threadIdx.x;
  __shared__ float a_s[64][33];
  __shared__ __align__(16) float w_s[64][36];
  int tr = t>>3, tc = t&7;
  float4 acc = {0,0,0,0};
  for(int kc=0; kc<6; kc++){
    int k0 = kp*384 + kc*64;
    {
      int row = t>>3, kk0 = (t&7)*8;
      const float4* src = (const float4*)(cat + (long)(l0+row)*1536 + k0 + kk0);
      float4 v0 = src[0], v1 = src[1];
      a_s[kk0+0][row]=v0.x; a_s[kk0+1][row]=v0.y; a_s[kk0+2][row]=v0.z; a_s[kk0+3][row]=v0.w;
      a_s[kk0+4][row]=v1.x; a_s[kk0+5][row]=v1.y; a_s[kk0+6][row]=v1.z; a_s[kk0+7][row]=v1.w;
    }
    #pragma unroll
    for(int kk2=0; kk2<2; kk2++){
      int kk = (t>>3) + 32*kk2;
      *(float4*)&w_s[kk][(t&7)*4] = *(const float4*)(wout + (long)(k0+kk)*256 + c0 + (t&7)*4);
    }
    __syncthreads();
    #pragma unroll 8
    for(int kk=0; kk<64; kk++){
      float a0 = a_s[kk][tr];
      float4 b4 = *(const float4*)&w_s[kk][tc*4];
      acc.x+=a0*b4.x; acc.y+=a0*b4.y; acc.z+=a0*b4.z; acc.w+=a0*b4.w;
    }
    __syncthreads();
  }
  *(float4*)(pcat + ((long)kp*L + l0+tr)*256 + c0 + tc*4) = acc;
}

// ---------------- kernel 8b: reduce partials + bias ----------------
__global__ __launch_bounds__(256) void k_redout(const float* pcat, const float* bout, float* out){
  int i = blockIdx.x*256 + threadIdx.x;    // float4 index over 73728
  const float4* p = (const float4*)pcat;
  float4 a = p[i], b = p[i+73728], c = p[i+147456], d = p[i+221184];
  float4 bv = ((const float4*)bout)[i&63];
  float4 r;
  r.x = a.x+b.x+c.x+d.x+bv.x;
  r.y = a.y+b.y+c.y+d.y+bv.y;
  r.z = a.z+b.z+c.z+d.z+bv.z;
  r.w = a.w+b.w+c.w+d.w+bv.w;
  ((float4*)out)[i] = r;
}

extern "C" void kernel_launch(void* const* d_in, const int* in_sizes, int n_in,
                              void* d_out, int out_size, void* d_ws, size_t ws_size,
                              hipStream_t stream) {
  const float* s      = (const float*)d_in[0];
  const float* z      = (const float*)d_in[1];
  const float* rot    = (const float*)d_in[2];
  const float* trans  = (const float*)d_in[3];
  const float* mask   = (const float*)d_in[4];
  const float* lnss   = (const float*)d_in[5];
  const float* lnsb   = (const float*)d_in[6];
  const float* lnzs   = (const float*)d_in[7];
  const float* lnzb   = (const float*)d_in[8];
  const float* wq     = (const float*)d_in[9];
  const float* wk     = (const float*)d_in[10];
  const float* wv     = (const float*)d_in[11];
  const float* wqp    = (const float*)d_in[12];
  const float* wkp    = (const float*)d_in[13];
  const float* wvp    = (const float*)d_in[14];
  const float* wb     = (const float*)d_in[15];
  const float* hws    = (const float*)d_in[16];
  const float* wout   = (const float*)d_in[17];
  const float* bout   = (const float*)d_in[18];
  const int*  ridx    = (const int*)d_in[19];

  float* ws  = (float*)d_ws;
  float* out = (float*)d_out;

  float* sln  = ws + OFF_SLN;
  float* proj = ws + OFF_PROJ;
  float* wpk  = ws + OFF_WPK;
  float* qcat = ws + OFF_QCAT;
  float* kcat = ws + OFF_KCAT;
  float* vcat = ws + OFF_VCAT;
  float* bres = ws + OFF_BRES;
  float* murs = ws + OFF_MURS;
  float* attn = ws + OFF_ATTN;
  float* cat  = ws + OFF_CAT;
  float* pcat = ws + OFF_PCAT;
  float* rstat= ws + OFF_RSTAT;
  float* pav  = ws + OFF_PAV;    // aliases sln/proj/wpk (dead by then)
  float* po   = ws + OFF_POP;    // aliases pav region after k_avred

  k_packw<<<dim3(256), dim3(256), 0, stream>>>(wq, wk, wv, wqp, wkp, wvp, wpk);
  k_ln_s<<<dim3(L), dim3(CS), 0, stream>>>(s, lnss, lnsb, sln);
  k_proj<<<dim3(18,17), dim3(256), 0, stream>>>(sln, wpk, proj);
  k_ln_z<<<dim3(NRES*NRES/32), dim3(256), 0, stream>>>(z, lnzs, lnzb, wb, murs, bres);
  k_rigid<<<dim3(L), dim3(256), 0, stream>>>(proj, rot, trans, mask, hws, qcat, kcat, vcat);
  k_scores<<<dim3(L/32, L/64, H), dim3(256), 0, stream>>>(qcat, kcat, bres, ridx, attn);
  k_rowstat<<<dim3(H*L/4), dim3(256), 0, stream>>>(attn, rstat);
  k_av<<<dim3(L/32, H, 3), dim3(256), 0, stream>>>(attn, vcat, rstat, pav);
  k_avred<<<dim3(L/32, H), dim3(256), 0, stream>>>(pav, rot, trans, cat);
  k_opair<<<dim3(NRES, 2), dim3(256), 0, stream>>>(attn, z, murs, rstat, lnzs, lnzb, ridx, po);
  k_opred<<<dim3(1152), dim3(256), 0, stream>>>(po, cat);
  k_final<<<dim3(36,8,4), dim3(256), 0, stream>>>(cat, wout, pcat);
  k_redout<<<dim3(288), dim3(256), 0, stream>>>(pcat, bout, out);
}